// Round 12
// baseline (970.561 us; speedup 1.0000x reference)
//
#include <hip/hip_runtime.h>
#include <hip/hip_bf16.h>
#include <cstdint>

// DeltaNet forward, MI355X. Round 12: GEMM LDS -> single-buffered (48/64KB)
// for 2 blocks/CU occupancy; 3-region tile schedule with overlapped drain.

typedef _Float16 f16;
typedef __attribute__((ext_vector_type(8))) _Float16 h8;
typedef __attribute__((ext_vector_type(4))) _Float16 h4;
typedef __attribute__((ext_vector_type(4))) float f4;

#define DEV __device__ __forceinline__

static constexpr int Bb_ = 4;
static constexpr int Hh  = 8;
static constexpr int Dd  = 1024;
static constexpr int Tt  = 2048;
static constexpr int NC  = 32;

DEV float siluf(float x) { return x / (1.f + expf(-x)); }
DEV int swz16(int row, int c) { return (c & 8) | ((c & 7) ^ (row & 7)); }

#define AS1(p) ((const __attribute__((address_space(1))) void*)(uintptr_t)(p))
#define AS3(p) ((__attribute__((address_space(3))) void*)(uint32_t)(uintptr_t)(p))

DEV h8 rd_sw(const f16* T, int row, int chunk) {
  return *(const h8*)(T + (((row << 3) | (chunk ^ (row & 7))) * 8));
}

// ====== 3-region single-buffered GEMM: C[M,N] op= A[M,K]*Bt[N,K]^T, BN=128 ==
// EPI 1: f16 += ; EPI 2: f16 store (xSC row-scale).
template<int EPI, int SC>
__global__ __launch_bounds__(512, 2) void gemm2(const f16* __restrict__ A, const f16* __restrict__ Bt,
                                                void* __restrict__ C, const float* __restrict__ rs,
                                                int M, int N, int K, int gx) {
  __shared__ __align__(16) f16 ldsA[16384];   // 256x64
  __shared__ __align__(16) f16 ldsB[8192];    // 128x64
  const int tid = threadIdx.x, lane = tid & 63, w = tid >> 6;
  const int l15 = lane & 15, l4 = lane >> 4;
  const int wr = w >> 2, wc = w & 3;
  const int nwg = gridDim.x;
  int flat = blockIdx.x;
  if ((nwg & 7) == 0) flat = (flat & 7) * (nwg >> 3) + (flat >> 3);
  const int bx = flat % gx, by = flat / gx;

  const f16* Ab = A + (size_t)by * 256 * K;
  const f16* Bb = Bt + (size_t)bx * 128 * K;
  const int NT = K >> 6;
  f4 acc[8][2] = {};

  const int r0 = tid >> 3;
  const size_t soff0 = (size_t)r0 * K + (size_t)(((tid & 7) ^ (r0 & 7)) * 8);
  const size_t soff1 = soff0 + (size_t)64 * K;
  const int dof = tid * 8;
  auto STG = [&](const f16* base, f16* dst) {
    __builtin_amdgcn_global_load_lds(AS1(base + soff0), AS3(dst + dof), 16, 0, 0);
    __builtin_amdgcn_global_load_lds(AS1(base + soff1), AS3(dst + 4096 + dof), 16, 0, 0);
  };

  STG(Bb, ldsB);
  STG(Ab, ldsA);
  STG(Ab + (size_t)128 * K, ldsA + 8192);
  asm volatile("s_waitcnt vmcnt(0)" ::: "memory");
  __builtin_amdgcn_s_barrier();

  for (int t = 0; t < NT; ++t) {
    h8 b[2][2], aX[2][2], aY[2][2];
    // ---- region 0: B-frags + A rows 0..63; MFMA half0 ----
#pragma unroll
    for (int cf = 0; cf < 2; ++cf)
#pragma unroll
      for (int ks = 0; ks < 2; ++ks)
        b[cf][ks] = rd_sw(ldsB, wc * 32 + cf * 16 + l15, ks * 4 + l4);
#pragma unroll
    for (int fr = 0; fr < 2; ++fr)
#pragma unroll
      for (int ks = 0; ks < 2; ++ks) {
        aX[fr][ks] = rd_sw(ldsA, wr * 128 + fr * 16 + l15, ks * 4 + l4);
        aY[fr][ks] = rd_sw(ldsA, wr * 128 + 32 + fr * 16 + l15, ks * 4 + l4);
      }
    __builtin_amdgcn_s_setprio(1);
#pragma unroll
    for (int fr = 0; fr < 2; ++fr)
#pragma unroll
      for (int cf = 0; cf < 2; ++cf)
#pragma unroll
        for (int ks = 0; ks < 2; ++ks) {
          acc[fr][cf] = __builtin_amdgcn_mfma_f32_16x16x32_f16(aX[fr][ks], b[cf][ks], acc[fr][cf], 0, 0, 0);
          acc[2 + fr][cf] = __builtin_amdgcn_mfma_f32_16x16x32_f16(aY[fr][ks], b[cf][ks], acc[2 + fr][cf], 0, 0, 0);
        }
    __builtin_amdgcn_s_setprio(0);
    __builtin_amdgcn_s_barrier();
    // ---- region 1a: A rows 64..127 reads, drained ----
#pragma unroll
    for (int fr = 0; fr < 2; ++fr)
#pragma unroll
      for (int ks = 0; ks < 2; ++ks) {
        aX[fr][ks] = rd_sw(ldsA, wr * 128 + 64 + fr * 16 + l15, ks * 4 + l4);
        aY[fr][ks] = rd_sw(ldsA, wr * 128 + 96 + fr * 16 + l15, ks * 4 + l4);
      }
    asm volatile("s_waitcnt lgkmcnt(0)" ::: "memory");
    __builtin_amdgcn_s_barrier();
    // ---- region 1b: stage(t+1) into same bufs; MFMA half1 overlaps DMA ----
    if (t + 1 < NT) {
      STG(Ab + (t + 1) * 64, ldsA);
      STG(Ab + (size_t)128 * K + (t + 1) * 64, ldsA + 8192);
      STG(Bb + (t + 1) * 64, ldsB);
    }
    __builtin_amdgcn_s_setprio(1);
#pragma unroll
    for (int fr = 0; fr < 2; ++fr)
#pragma unroll
      for (int cf = 0; cf < 2; ++cf)
#pragma unroll
        for (int ks = 0; ks < 2; ++ks) {
          acc[4 + fr][cf] = __builtin_amdgcn_mfma_f32_16x16x32_f16(aX[fr][ks], b[cf][ks], acc[4 + fr][cf], 0, 0, 0);
          acc[6 + fr][cf] = __builtin_amdgcn_mfma_f32_16x16x32_f16(aY[fr][ks], b[cf][ks], acc[6 + fr][cf], 0, 0, 0);
        }
    __builtin_amdgcn_s_setprio(0);
    if (t + 1 < NT) asm volatile("s_waitcnt vmcnt(0)" ::: "memory");
    __builtin_amdgcn_s_barrier();
  }

#pragma unroll
  for (int fr = 0; fr < 8; ++fr) {
#pragma unroll
    for (int cf = 0; cf < 2; ++cf) {
      const int row0 = by * 256 + wr * 128 + fr * 16 + l4 * 4;
      const int col = bx * 128 + wc * 32 + cf * 16 + l15;
#pragma unroll
      for (int q = 0; q < 4; ++q) {
        const size_t idx = (size_t)(row0 + q) * N + col;
        float v = acc[fr][cf][q];
        if (SC) v *= rs[row0 + q];
        if (EPI == 1) ((f16*)C)[idx] = (f16)((float)((f16*)C)[idx] + v);
        if (EPI == 2) ((f16*)C)[idx] = (f16)v;
      }
    }
  }
}

// ============ QKV GEMM (single-buffered) with fused silu+l2norm epilogue ====
__global__ __launch_bounds__(512, 2) void gemmQKV(const f16* __restrict__ A, const f16* __restrict__ Bt,
                                                  const float* __restrict__ rs, f16* __restrict__ qb,
                                                  f16* __restrict__ kb, f16* __restrict__ vb,
                                                  int K, int gx) {
  __shared__ __align__(16) f16 ldsA[16384];
  __shared__ __align__(16) f16 ldsB[8192];
  __shared__ float ps[4][256];
  const int tid = threadIdx.x, lane = tid & 63, w = tid >> 6;
  const int l15 = lane & 15, l4 = lane >> 4;
  const int wr = w >> 2, wc = w & 3;
  const int nwg = gridDim.x;
  int flat = blockIdx.x;
  if ((nwg & 7) == 0) flat = (flat & 7) * (nwg >> 3) + (flat >> 3);
  const int bx = flat % gx, by = flat / gx;

  const f16* Ab = A + (size_t)by * 256 * K;
  const f16* Bb = Bt + (size_t)bx * 128 * K;
  const int NT = K >> 6;
  f4 acc[8][2] = {};

  const int r0 = tid >> 3;
  const size_t soff0 = (size_t)r0 * K + (size_t)(((tid & 7) ^ (r0 & 7)) * 8);
  const size_t soff1 = soff0 + (size_t)64 * K;
  const int dof = tid * 8;
  auto STG = [&](const f16* base, f16* dst) {
    __builtin_amdgcn_global_load_lds(AS1(base + soff0), AS3(dst + dof), 16, 0, 0);
    __builtin_amdgcn_global_load_lds(AS1(base + soff1), AS3(dst + 4096 + dof), 16, 0, 0);
  };

  STG(Bb, ldsB);
  STG(Ab, ldsA);
  STG(Ab + (size_t)128 * K, ldsA + 8192);
  asm volatile("s_waitcnt vmcnt(0)" ::: "memory");
  __builtin_amdgcn_s_barrier();

  for (int t = 0; t < NT; ++t) {
    h8 b[2][2], aX[2][2], aY[2][2];
#pragma unroll
    for (int cf = 0; cf < 2; ++cf)
#pragma unroll
      for (int ks = 0; ks < 2; ++ks)
        b[cf][ks] = rd_sw(ldsB, wc * 32 + cf * 16 + l15, ks * 4 + l4);
#pragma unroll
    for (int fr = 0; fr < 2; ++fr)
#pragma unroll
      for (int ks = 0; ks < 2; ++ks) {
        aX[fr][ks] = rd_sw(ldsA, wr * 128 + fr * 16 + l15, ks * 4 + l4);
        aY[fr][ks] = rd_sw(ldsA, wr * 128 + 32 + fr * 16 + l15, ks * 4 + l4);
      }
    __builtin_amdgcn_s_setprio(1);
#pragma unroll
    for (int fr = 0; fr < 2; ++fr)
#pragma unroll
      for (int cf = 0; cf < 2; ++cf)
#pragma unroll
        for (int ks = 0; ks < 2; ++ks) {
          acc[fr][cf] = __builtin_amdgcn_mfma_f32_16x16x32_f16(aX[fr][ks], b[cf][ks], acc[fr][cf], 0, 0, 0);
          acc[2 + fr][cf] = __builtin_amdgcn_mfma_f32_16x16x32_f16(aY[fr][ks], b[cf][ks], acc[2 + fr][cf], 0, 0, 0);
        }
    __builtin_amdgcn_s_setprio(0);
    __builtin_amdgcn_s_barrier();
#pragma unroll
    for (int fr = 0; fr < 2; ++fr)
#pragma unroll
      for (int ks = 0; ks < 2; ++ks) {
        aX[fr][ks] = rd_sw(ldsA, wr * 128 + 64 + fr * 16 + l15, ks * 4 + l4);
        aY[fr][ks] = rd_sw(ldsA, wr * 128 + 96 + fr * 16 + l15, ks * 4 + l4);
      }
    asm volatile("s_waitcnt lgkmcnt(0)" ::: "memory");
    __builtin_amdgcn_s_barrier();
    if (t + 1 < NT) {
      STG(Ab + (t + 1) * 64, ldsA);
      STG(Ab + (size_t)128 * K + (t + 1) * 64, ldsA + 8192);
      STG(Bb + (t + 1) * 64, ldsB);
    }
    __builtin_amdgcn_s_setprio(1);
#pragma unroll
    for (int fr = 0; fr < 2; ++fr)
#pragma unroll
      for (int cf = 0; cf < 2; ++cf)
#pragma unroll
        for (int ks = 0; ks < 2; ++ks) {
          acc[4 + fr][cf] = __builtin_amdgcn_mfma_f32_16x16x32_f16(aX[fr][ks], b[cf][ks], acc[4 + fr][cf], 0, 0, 0);
          acc[6 + fr][cf] = __builtin_amdgcn_mfma_f32_16x16x32_f16(aY[fr][ks], b[cf][ks], acc[6 + fr][cf], 0, 0, 0);
        }
    __builtin_amdgcn_s_setprio(0);
    if (t + 1 < NT) asm volatile("s_waitcnt vmcnt(0)" ::: "memory");
    __builtin_amdgcn_s_barrier();
  }

  // ---- epilogue: silu(rs*acc); Q/K per-row l2norm over head; scatter ----
#pragma unroll
  for (int fr = 0; fr < 8; ++fr)
#pragma unroll
    for (int q = 0; q < 4; ++q) {
      const int grow = by * 256 + wr * 128 + fr * 16 + l4 * 4 + q;
      const float s = rs[grow];
#pragma unroll
      for (int cf = 0; cf < 2; ++cf)
        acc[fr][cf][q] = siluf(s * acc[fr][cf][q]);
    }
  if (bx < 16) {
    float sq[8][4];
#pragma unroll
    for (int fr = 0; fr < 8; ++fr)
#pragma unroll
      for (int q = 0; q < 4; ++q) {
        float v = acc[fr][0][q] * acc[fr][0][q] + acc[fr][1][q] * acc[fr][1][q];
#pragma unroll
        for (int m = 1; m < 16; m <<= 1) v += __shfl_xor(v, m);
        sq[fr][q] = v;
      }
    if (l15 == 0) {
#pragma unroll
      for (int fr = 0; fr < 8; ++fr)
#pragma unroll
        for (int q = 0; q < 4; ++q)
          ps[wc][wr * 128 + fr * 16 + l4 * 4 + q] = sq[fr][q];
    }
    __syncthreads();
#pragma unroll
    for (int fr = 0; fr < 8; ++fr)
#pragma unroll
      for (int q = 0; q < 4; ++q) {
        const int rl = wr * 128 + fr * 16 + l4 * 4 + q;
        const float sc = rsqrtf(ps[0][rl] + ps[1][rl] + ps[2][rl] + ps[3][rl] + 1e-6f);
#pragma unroll
        for (int cf = 0; cf < 2; ++cf) acc[fr][cf][q] *= sc;
      }
  }
  f16* dst = (bx < 8) ? qb : ((bx < 16) ? kb : vb);
  const int head = bx & 7;
#pragma unroll
  for (int fr = 0; fr < 8; ++fr)
#pragma unroll
    for (int cf = 0; cf < 2; ++cf)
#pragma unroll
      for (int q = 0; q < 4; ++q) {
        const int grow = by * 256 + wr * 128 + fr * 16 + l4 * 4 + q;
        const int i = (grow >> 2) & 63;
        const int dh = wc * 32 + cf * 16 + l15;
        dst[(size_t)grow * 1024 + head * 128 + swz16(i, dh >> 3) * 8 + (dh & 7)] = (f16)acc[fr][cf][q];
      }
}

// ============ fused GLU GEMM (single-buffered, 64KB) ========================
__global__ __launch_bounds__(512, 2) void gemmGLU(const f16* __restrict__ A, const f16* __restrict__ WgT,
                                                  const float* __restrict__ rs, f16* __restrict__ my,
                                                  int K, int gx) {
  __shared__ __align__(16) f16 ldsA[16384];
  __shared__ __align__(16) f16 ldsG[8192];
  __shared__ __align__(16) f16 ldsY[8192];
  const int tid = threadIdx.x, lane = tid & 63, w = tid >> 6;
  const int l15 = lane & 15, l4 = lane >> 4;
  const int wr = w >> 2, wc = w & 3;
  const int nwg = gridDim.x;
  int flat = blockIdx.x;
  if ((nwg & 7) == 0) flat = (flat & 7) * (nwg >> 3) + (flat >> 3);
  const int bx = flat % gx, by = flat / gx;

  const f16* Ab = A + (size_t)by * 256 * K;
  const f16* Gb = WgT + (size_t)bx * 128 * K;
  const f16* Yb = WgT + (size_t)(2816 + bx * 128) * K;
  const int NT = K >> 6;
  f4 accG[8][2] = {}, accY[8][2] = {};

  const int r0 = tid >> 3;
  const size_t soff0 = (size_t)r0 * K + (size_t)(((tid & 7) ^ (r0 & 7)) * 8);
  const size_t soff1 = soff0 + (size_t)64 * K;
  const int dof = tid * 8;
  auto STG = [&](const f16* base, f16* dst) {
    __builtin_amdgcn_global_load_lds(AS1(base + soff0), AS3(dst + dof), 16, 0, 0);
    __builtin_amdgcn_global_load_lds(AS1(base + soff1), AS3(dst + 4096 + dof), 16, 0, 0);
  };

  STG(Gb, ldsG);
  STG(Yb, ldsY);
  STG(Ab, ldsA);
  STG(Ab + (size_t)128 * K, ldsA + 8192);
  asm volatile("s_waitcnt vmcnt(0)" ::: "memory");
  __builtin_amdgcn_s_barrier();

  for (int t = 0; t < NT; ++t) {
    h8 bg[2][2], byv[2][2], aX[2][2], aY[2][2];
#pragma unroll
    for (int cf = 0; cf < 2; ++cf)
#pragma unroll
      for (int ks = 0; ks < 2; ++ks) {
        bg[cf][ks] = rd_sw(ldsG, wc * 32 + cf * 16 + l15, ks * 4 + l4);
        byv[cf][ks] = rd_sw(ldsY, wc * 32 + cf * 16 + l15, ks * 4 + l4);
      }
#pragma unroll
    for (int fr = 0; fr < 2; ++fr)
#pragma unroll
      for (int ks = 0; ks < 2; ++ks) {
        aX[fr][ks] = rd_sw(ldsA, wr * 128 + fr * 16 + l15, ks * 4 + l4);
        aY[fr][ks] = rd_sw(ldsA, wr * 128 + 32 + fr * 16 + l15, ks * 4 + l4);
      }
    __builtin_amdgcn_s_setprio(1);
#pragma unroll
    for (int fr = 0; fr < 2; ++fr)
#pragma unroll
      for (int cf = 0; cf < 2; ++cf)
#pragma unroll
        for (int ks = 0; ks < 2; ++ks) {
          accG[fr][cf] = __builtin_amdgcn_mfma_f32_16x16x32_f16(aX[fr][ks], bg[cf][ks], accG[fr][cf], 0, 0, 0);
          accY[fr][cf] = __builtin_amdgcn_mfma_f32_16x16x32_f16(aX[fr][ks], byv[cf][ks], accY[fr][cf], 0, 0, 0);
          accG[2 + fr][cf] = __builtin_amdgcn_mfma_f32_16x16x32_f16(aY[fr][ks], bg[cf][ks], accG[2 + fr][cf], 0, 0, 0);
          accY[2 + fr][cf] = __builtin_amdgcn_mfma_f32_16x16x32_f16(aY[fr][ks], byv[cf][ks], accY[2 + fr][cf], 0, 0, 0);
        }
    __builtin_amdgcn_s_setprio(0);
    __builtin_amdgcn_s_barrier();
#pragma unroll
    for (int fr = 0; fr < 2; ++fr)
#pragma unroll
      for (int ks = 0; ks < 2; ++ks) {
        aX[fr][ks] = rd_sw(ldsA, wr * 128 + 64 + fr * 16 + l15, ks * 4 + l4);
        aY[fr][ks] = rd_sw(ldsA, wr * 128 + 96 + fr * 16 + l15, ks * 4 + l4);
      }
    asm volatile("s_waitcnt lgkmcnt(0)" ::: "memory");
    __builtin_amdgcn_s_barrier();
    if (t + 1 < NT) {
      STG(Ab + (t + 1) * 64, ldsA);
      STG(Ab + (size_t)128 * K + (t + 1) * 64, ldsA + 8192);
      STG(Gb + (t + 1) * 64, ldsG);
      STG(Yb + (t + 1) * 64, ldsY);
    }
    __builtin_amdgcn_s_setprio(1);
#pragma unroll
    for (int fr = 0; fr < 2; ++fr)
#pragma unroll
      for (int cf = 0; cf < 2; ++cf)
#pragma unroll
        for (int ks = 0; ks < 2; ++ks) {
          accG[4 + fr][cf] = __builtin_amdgcn_mfma_f32_16x16x32_f16(aX[fr][ks], bg[cf][ks], accG[4 + fr][cf], 0, 0, 0);
          accY[4 + fr][cf] = __builtin_amdgcn_mfma_f32_16x16x32_f16(aX[fr][ks], byv[cf][ks], accY[4 + fr][cf], 0, 0, 0);
          accG[6 + fr][cf] = __builtin_amdgcn_mfma_f32_16x16x32_f16(aY[fr][ks], bg[cf][ks], accG[6 + fr][cf], 0, 0, 0);
          accY[6 + fr][cf] = __builtin_amdgcn_mfma_f32_16x16x32_f16(aY[fr][ks], byv[cf][ks], accY[6 + fr][cf], 0, 0, 0);
        }
    __builtin_amdgcn_s_setprio(0);
    if (t + 1 < NT) asm volatile("s_waitcnt vmcnt(0)" ::: "memory");
    __builtin_amdgcn_s_barrier();
  }

#pragma unroll
  for (int fr = 0; fr < 8; ++fr) {
#pragma unroll
    for (int cf = 0; cf < 2; ++cf) {
      const int row0 = by * 256 + wr * 128 + fr * 16 + l4 * 4;
      const int col = bx * 128 + wc * 32 + cf * 16 + l15;
#pragma unroll
      for (int q = 0; q < 4; ++q) {
        const float s = rs[row0 + q];
        my[(size_t)(row0 + q) * 2816 + col] = (f16)(siluf(s * accG[fr][cf][q]) * (s * accY[fr][cf][q]));
      }
    }
  }
}

// ---------------- f32 -> f16 convert ---------------------------------------
__global__ __launch_bounds__(256) void cvt_k(const float* __restrict__ in, f16* __restrict__ out) {
  const size_t i = ((size_t)blockIdx.x * 256 + threadIdx.x) * 8;
  const float4 a = *(const float4*)(in + i);
  const float4 b = *(const float4*)(in + i + 4);
  h8 o = {(f16)a.x, (f16)a.y, (f16)a.z, (f16)a.w, (f16)b.x, (f16)b.y, (f16)b.z, (f16)b.w};
  *(h8*)(out + i) = o;
}

// ---------------- per-row rsqrt(mean(x^2)+eps) -----------------------------
__global__ __launch_bounds__(256) void rowscale_k(const f16* __restrict__ x, float* __restrict__ rs) {
  const int tid = threadIdx.x, lane = tid & 63, wv = tid >> 6;
  const int r = blockIdx.x * 4 + wv;
  const f16* row = x + (size_t)r * 1024 + lane * 16;
  const h8 v0 = *(const h8*)(row);
  const h8 v1 = *(const h8*)(row + 8);
  float ss = 0.f;
#pragma unroll
  for (int e = 0; e < 8; ++e) {
    const float a = (float)v0[e], b = (float)v1[e];
    ss += a * a + b * b;
  }
#pragma unroll
  for (int m = 1; m < 64; m <<= 1) ss += __shfl_xor(ss, m);
  if (lane == 0) rs[r] = rsqrtf(ss * (1.f / 1024.f) + 1e-6f);
}

// ---------------- final RMSNorm (f16 in, f32 out) --------------------------
__global__ __launch_bounds__(256) void rmsnorm_f(const f16* __restrict__ x, const float* __restrict__ w,
                                                 float* __restrict__ out) {
  const int r = blockIdx.x, tid = threadIdx.x;
  const h4 xv = *(const h4*)(x + (size_t)r * 1024 + tid * 4);
  const float v0 = (float)xv[0], v1 = (float)xv[1], v2 = (float)xv[2], v3 = (float)xv[3];
  float ss = v0 * v0 + v1 * v1 + v2 * v2 + v3 * v3;
#pragma unroll
  for (int m = 1; m < 64; m <<= 1) ss += __shfl_xor(ss, m);
  __shared__ float red[4];
  if ((tid & 63) == 0) red[tid >> 6] = ss;
  __syncthreads();
  const float scale = rsqrtf((red[0] + red[1] + red[2] + red[3]) * (1.f / 1024.f) + 1e-6f);
  const float4 w4 = *(const float4*)(w + tid * 4);
  *(float4*)(out + (size_t)r * 1024 + tid * 4) =
      make_float4(v0 * scale * w4.x, v1 * scale * w4.y, v2 * scale * w4.z, v3 * scale * w4.w);
}

// ---------------- per-head RMSNorm -----------------------------------------
__global__ __launch_bounds__(256) void onorm_k(const f16* __restrict__ o, const float* __restrict__ w,
                                               f16* __restrict__ ob) {
  const int r = blockIdx.x, tid = threadIdx.x;
  const int head = tid >> 5, l32 = tid & 31;
  const size_t base = (size_t)r * 1024 + head * 128 + l32 * 4;
  const h4 xv = *(const h4*)(o + base);
  const float v0 = (float)xv[0], v1 = (float)xv[1], v2 = (float)xv[2], v3 = (float)xv[3];
  float ss = v0 * v0 + v1 * v1 + v2 * v2 + v3 * v3;
#pragma unroll
  for (int m = 1; m <= 16; m <<= 1) ss += __shfl_xor(ss, m);
  const float sc = rsqrtf(ss * (1.f / 128.f) + 1e-6f);
  const float4 w4 = *(const float4*)(w + l32 * 4);
  h4 out = {(f16)(v0 * sc * w4.x), (f16)(v1 * sc * w4.y), (f16)(v2 * sc * w4.z), (f16)(v3 * sc * w4.w)};
  *(h4*)(ob + base) = out;
}

// ---------------- beta = 2*sigmoid(s * (x @ Wb')) --------------------------
__global__ __launch_bounds__(256) void beta_k(const f16* __restrict__ x, const float* __restrict__ Wb2,
                                              const float* __restrict__ rs, float* __restrict__ beta) {
  const int tid = threadIdx.x, lane = tid & 63, wv = tid >> 6;
  const int r = blockIdx.x * 4 + wv;
  const f16* row = x + (size_t)r * 1024 + lane * 16;
  const h8 v0 = *(const h8*)(row);
  const h8 v1 = *(const h8*)(row + 8);
  const float* wb = Wb2 + (size_t)(lane * 16) * 8;
  float acc[8] = {};
#pragma unroll
  for (int e = 0; e < 8; ++e) {
    const float x0 = (float)v0[e], x1 = (float)v1[e];
    const float4 w0a = *(const float4*)(wb + e * 8);
    const float4 w0b = *(const float4*)(wb + e * 8 + 4);
    const float4 w1a = *(const float4*)(wb + (e + 8) * 8);
    const float4 w1b = *(const float4*)(wb + (e + 8) * 8 + 4);
    acc[0] += x0 * w0a.x + x1 * w1a.x;  acc[1] += x0 * w0a.y + x1 * w1a.y;
    acc[2] += x0 * w0a.z + x1 * w1a.z;  acc[3] += x0 * w0a.w + x1 * w1a.w;
    acc[4] += x0 * w0b.x + x1 * w1b.x;  acc[5] += x0 * w0b.y + x1 * w1b.y;
    acc[6] += x0 * w0b.z + x1 * w1b.z;  acc[7] += x0 * w0b.w + x1 * w1b.w;
  }
#pragma unroll
  for (int j = 0; j < 8; ++j)
#pragma unroll
    for (int m = 1; m < 64; m <<= 1) acc[j] += __shfl_xor(acc[j], m);
  if (lane == 0) {
    const float s = rs[r];
#pragma unroll
    for (int j = 0; j < 8; ++j) beta[(size_t)r * 8 + j] = 2.f / (1.f + expf(-acc[j] * s));
  }
}

// ---------------- W[K][N] f32 -> Wt[N][K] f16 (opt row-weight fold) --------
template<int FOLD>
__global__ __launch_bounds__(256) void transpose_k(const float* __restrict__ W, const float* __restrict__ rw,
                                                   f16* __restrict__ Wt, int K, int N) {
  __shared__ float tile[32][33];
  const int n0 = blockIdx.x * 32, k0 = blockIdx.y * 32;
  const int tx = threadIdx.x & 31, ty = threadIdx.x >> 5;
#pragma unroll
  for (int i = 0; i < 32; i += 8) {
    float v = W[(size_t)(k0 + ty + i) * N + n0 + tx];
    if (FOLD) v *= rw[k0 + ty + i];
    tile[ty + i][tx] = v;
  }
  __syncthreads();
#pragma unroll
  for (int i = 0; i < 32; i += 8) Wt[(size_t)(n0 + ty + i) * K + k0 + tx] = (f16)tile[tx][ty + i];
}

// ---------------- Wb' = diag(n1w) Wb ---------------------------------------
__global__ __launch_bounds__(256) void bweight_k(const float* __restrict__ Wb, const float* __restrict__ n1w,
                                                 float* __restrict__ Wb2) {
  const int idx = blockIdx.x * 256 + threadIdx.x;
  Wb2[idx] = Wb[idx] * n1w[idx >> 3];
}

__global__ void fill_k(float* p, int n, float v) {
  const int i = blockIdx.x * 256 + threadIdx.x;
  if (i < n) p[i] = v;
}

// ---------------- Phase A: WY transform ------------------------------------
DEV f4 mm16(const f16* A, int as, const f16* B, f4 c, int l15, int l4) {
  h4 a = *(const h4*)(A + l15 * as + l4 * 4);
  h4 b = *(const h4*)(B + l15 * 20 + l4 * 4);
  return __builtin_amdgcn_mfma_f32_16x16x16f16(a, b, c, 0, 0, 0);
}
DEV void wr_T(f16* slot, f4 acc, int l15, int l4, float sgn) {
  h4 v = {(f16)(sgn * acc[0]), (f16)(sgn * acc[1]), (f16)(sgn * acc[2]), (f16)(sgn * acc[3])};
  *(h4*)(slot + l15 * 20 + l4 * 4) = v;
}
DEV void wr_Tb(f16* Tb, int bi, int bj, f4 acc, const float* betas, int l15, int l4, float sgn) {
  const float bc = betas[bj * 16 + l15];
#pragma unroll
  for (int q = 0; q < 4; ++q)
    Tb[(bi * 16 + l4 * 4 + q) * 72 + bj * 16 + l15] = (f16)(sgn * acc[q] * bc);
}

__global__ __launch_bounds__(256) void phaseA(const f16* __restrict__ kb, const f16* __restrict__ qb,
                                              const f16* __restrict__ vb, const float* __restrict__ beta,
                                              f16* __restrict__ wbuf, f16* __restrict__ utbuf,
                                              f16* __restrict__ pbuf, f16* __restrict__ ktbuf) {
  const int blk = blockIdx.x;
  const int c = blk >> 5, bh = blk & 31;
  const int b = bh >> 3, h = bh & 7;
  const int tid = threadIdx.x, lane = tid & 63, wv = tid >> 6;
  const int l15 = lane & 15, l4 = lane >> 4;

  __shared__ __align__(16) f16 Ks[64 * 128];
  __shared__ __align__(16) f16 QVs[64 * 128];
  __shared__ __align__(16) f16 Abuf[64 * 68];
  __shared__ __align__(16) f16 Dr[4][16 * 20];
  __shared__ __align__(16) f16 Dt[4][16 * 20];
  __shared__ __align__(16) f16 Tp[3][16 * 20];
  __shared__ __align__(16) f16 Xp[3][16 * 20];
  __shared__ __align__(16) f16 Tb[64 * 72];
  __shared__ float betas[64];

  const size_t rowstr = (size_t)Bb_ * Dd;
  const size_t gbase = ((size_t)(c * 64) * Bb_ + b) * Dd + h * 128;

#pragma unroll
  for (int i = 0; i < 4; ++i) {
    const int ch = tid + i * 256;
    const int rr = ch >> 4, kc = ch & 15;
    *(h8*)(Ks + ch * 8) = *(const h8*)(kb + gbase + (size_t)rr * rowstr + kc * 8);
    *(h8*)(QVs + ch * 8) = *(const h8*)(qb + gbase + (size_t)rr * rowstr + kc * 8);
  }
  for (int i = tid; i < 64 * 72; i += 256) Tb[i] = (f16)0.f;
  if (tid < 64) betas[tid] = beta[((size_t)(c * 64 + tid) * Bb_ + b) * Hh + h];
  __syncthreads();

  f4 accS[4] = {}, accP[4] = {};
  const int arow = wv * 16 + l15;
#pragma unroll
  for (int kc = 0; kc < 4; ++kc) {
    const int c4 = kc * 4 + l4;
    const h8 aK = *(const h8*)(Ks + arow * 128 + swz16(arow, c4) * 8);
    const h8 aQ = *(const h8*)(QVs + arow * 128 + swz16(arow, c4) * 8);
#pragma unroll
    for (int f = 0; f < 4; ++f) {
      const int brow = f * 16 + l15;
      const h8 bK = *(const h8*)(Ks + brow * 128 + swz16(brow, c4) * 8);
      accS[f] = __builtin_amdgcn_mfma_f32_16x16x32_f16(aK, bK, accS[f], 0, 0, 0);
      accP[f] = __builtin_amdgcn_mfma_f32_16x16x32_f16(aQ, bK, accP[f], 0, 0, 0);
    }
  }
  const size_t pbase = (((size_t)bh * NC + c) * 64) * 64;
#pragma unroll
  for (int f = 0; f < 4; ++f) {
#pragma unroll
    for (int q = 0; q < 4; ++q) {
      const int i = wv * 16 + l4 * 4 + q;
      const int j = f * 16 + l15;
      Abuf[i * 68 + j] = (f16)((j < i) ? betas[i] * accS[f][q] : 0.f);
      pbuf[pbase + (size_t)i * 64 + j] = (f16)((j <= i) ? accP[f][q] : 0.f);
    }
  }
  __syncthreads();

#pragma unroll
  for (int i = 0; i < 4; ++i) {
    const int ch = tid + i * 256;
    const int rr = ch >> 4, kc = ch & 15;
    *(h8*)(QVs + ch * 8) = *(const h8*)(vb + gbase + (size_t)rr * rowstr + kc * 8);
  }

  {
    const int bi = wv;
    const int cc = l15;
    const f16* Ad = Abuf + (bi * 16) * 68 + bi * 16;
    float t[16];
    t[0] = (cc == 0) ? 1.f : 0.f;
#pragma unroll
    for (int i = 1; i < 16; ++i) {
      float s = (cc == i) ? 1.f : 0.f;
#pragma unroll
      for (int j = 0; j < i; ++j) s -= (float)Ad[i * 68 + j] * t[j];
      t[i] = s;
    }
    if (lane < 16) {
#pragma unroll
      for (int j4 = 0; j4 < 4; ++j4) {
        h4 v = {(f16)t[j4 * 4], (f16)t[j4 * 4 + 1], (f16)t[j4 * 4 + 2], (f16)t[j4 * 4 + 3]};
        *(h4*)(&Dt[bi][cc * 20 + j4 * 4]) = v;
      }
      const float bc = betas[bi * 16 + cc];
#pragma unroll
      for (int j = 0; j < 16; ++j) {
        Dr[bi][j * 20 + cc] = (f16)t[j];
        Tb[(bi * 16 + j) * 72 + bi * 16 + cc] = (f16)(t[j] * bc);
      }
    }
  }
  __syncthreads();

  const f16* AB10 = Abuf + 16 * 68 + 0;
  const f16* AB20 = Abuf + 32 * 68 + 0;
  const f16* AB21 = Abuf + 32 * 68 + 16;
  const f16* AB30 = Abuf + 48 * 68 + 0;
  const f16* AB31 = Abuf + 48 * 68 + 16;
  const f16* AB32 = Abuf + 48 * 68 + 32;
  f4 z = {};
  f4 x20, x30;

  if (wv == 0) wr_T(Xp[0], mm16(AB10, 68, Dt[0], z, l15, l4), l15, l4, 1.f);
  if (wv == 1) wr_T(Xp[1], mm16(AB21, 68, Dt[1], z, l15, l4), l15, l4, 1.f);
  if (wv == 2) wr_T(Xp[2], mm16(AB32, 68, Dt[2], z, l15, l4), l15, l4, 1.f);
  if (wv == 3) x20 = mm16(AB20, 68, Dt[0], z, l15, l4);
  __syncthreads();
  if (wv == 0) { f4 r = mm16(Dr[1], 20, Xp[0], z, l15, l4); wr_T(Tp[0], r, l15, l4, -1.f); wr_Tb(Tb, 1, 0, r, betas, l15, l4, -1.f); }
  if (wv == 1) { f4 r = mm16(Dr[2], 20, Xp[1], z, l15, l4); wr_T(Tp[1], r, l15, l4, -1.f); wr_Tb(Tb, 2, 1, r, betas, l15, l4, -1.f); }
  if (wv == 2) { f4 r = mm16(Dr[3], 20, Xp[2], z, l15, l4); wr_Tb(Tb, 3, 2, r, betas, l15, l4, -1.f); }
  if (wv == 3) x30 = mm16(AB30, 68, Dt[0], z, l15, l4);
  __syncthreads();
  if (wv == 3) wr_T(Xp[0], mm16(AB21, 68, Tp[0], x20, l15, l4), l15, l4, 1.f);
  if (wv == 1) { f4 r = mm16(AB31, 68, Dt[1], z, l15, l4); r = mm16(AB32, 68, Tp[1], r, l15, l4); wr_T(Xp[1], r, l15, l4, 1.f); }
  __syncthreads();
  if (wv == 3) { f4 r = mm16(Dr[2], 20, Xp[0], z, l15, l4); wr_T(Tp[2], r, l15, l4, -1.f); wr_Tb(Tb, 2, 0, r, betas, l15, l4, -1.f); }
  if (wv == 1) { f4 r = mm16(Dr[3], 20, Xp[1], z, l15, l4); wr_Tb(Tb, 3, 1, r, betas, l15, l4, -1.f); }
  __syncthreads();
  if (wv == 3) { f4 r = mm16(AB31, 68, Tp[0], x30, l15, l4); r = mm16(AB32, 68, Tp[2], r, l15, l4); wr_T(Xp[2], r, l15, l4, 1.f); }
  __syncthreads();
  if (wv == 3) { f4 r = mm16(Dr[3], 20, Xp[2], z, l15, l4); wr_Tb(Tb, 3, 0, r, betas, l15, l4, -1.f); }
  __syncthreads();

  const size_t wub = ((size_t)bh * NC + c) * 8192;
  const int koff = l4 * 8;
  f4 wacc[8] = {}, uacc[8] = {};
#pragma unroll
  for (int kc = 0; kc < 2; ++kc) {
    const h8 aT = *(const h8*)(Tb + (wv * 16 + l15) * 72 + kc * 32 + koff);
#pragma unroll
    for (int f = 0; f < 8; ++f) {
      const int d = f * 16 + l15, cD = d >> 3, d7 = d & 7;
      h8 bK, bV;
#pragma unroll
      for (int j = 0; j < 8; ++j) {
        const int t2 = kc * 32 + koff + j;
        const int pos = t2 * 128 + swz16(t2, cD) * 8 + d7;
        bK[j] = Ks[pos];
        bV[j] = QVs[pos];
      }
      wacc[f] = __builtin_amdgcn_mfma_f32_16x16x32_f16(aT, bK, wacc[f], 0, 0, 0);
      uacc[f] = __builtin_amdgcn_mfma_f32_16x16x32_f16(aT, bV, uacc[f], 0, 0, 0);
    }
  }
#pragma unroll
  for (int f = 0; f < 8; ++f) {
    const int d = f * 16 + l15, cD = d >> 3, d7 = d & 7;
#pragma unroll
    for (int q = 0; q < 4; ++q) {
      const int i = wv * 16 + l4 * 4 + q;
      wbuf[wub + (size_t)i * 128 + swz16(i, cD) * 8 + d7] = (f16)wacc[f][q];
    }
    h4 uv = {(f16)uacc[f][0], (f16)uacc[f][1], (f16)uacc[f][2], (f16)uacc[f][3]};
    *(h4*)(utbuf + wub + (size_t)d * 64 + wv * 16 + l4 * 4) = uv;
  }

#pragma unroll
  for (int i2 = 0; i2 < 4; ++i2) {
    const int ch = tid + i2 * 256;
    const int dp = ch & 127, c2 = ch >> 7;
    h8 v;
#pragma unroll
    for (int j = 0; j < 8; ++j) {
      const int i = c2 * 8 + j;
      v[j] = Ks[i * 128 + swz16(i, dp >> 3) * 8 + (dp & 7)];
    }
    *(h8*)(ktbuf + wub + (size_t)dp * 64 + (c2 ^ (dp & 7)) * 8) = v;
  }
}

// ---------------- Phase B: chunk recurrence (g in 0..7, 16 cols) -----------
__global__ __launch_bounds__(256) void phaseB(const f16* __restrict__ qb, const f16* __restrict__ ktbuf,
                                              const f16* __restrict__ wbuf, const f16* __restrict__ utbuf,
                                              const f16* __restrict__ pbuf, f16* __restrict__ obuf) {
  const int blk = blockIdx.x;          // g*32 + bh
  const int bh = blk & 31, g = blk >> 5;
  const int b = bh >> 3, h = bh & 7;
  const int tid = threadIdx.x, lane = tid & 63, wv = tid >> 6;
  const int l15 = lane & 15, l4 = lane >> 4;

  __shared__ __align__(16) f16 Ws[2][8192];
  __shared__ __align__(16) f16 Qs[2][8192];
  __shared__ __align__(16) f16 Kts[2][8192];
  __shared__ __align__(16) f16 Rt[16 * 72];
  __shared__ __align__(16) f16 Ms[16 * 136];

  for (int i = tid; i < 16 * 136; i += 256) Ms[i] = (f16)0.f;
  f4 macc2[2] = {};

  const int arow = wv * 16 + l15;
  const int koff = l4 * 8;

  auto STAGE = [&](int c2, int buf) {
#pragma unroll
    for (int i = 0; i < 4; ++i) {
      const int ch = tid + i * 256;
      const size_t tb = ((size_t)bh * NC + c2) * 8192;
      __builtin_amdgcn_global_load_lds(AS1(wbuf + tb + ch * 8), AS3(Ws[buf] + ch * 8), 16, 0, 0);
      __builtin_amdgcn_global_load_lds(AS1(ktbuf + tb + ch * 8), AS3(Kts[buf] + ch * 8), 16, 0, 0);
      const int rr = ch >> 4, kc2 = ch & 15;
      __builtin_amdgcn_global_load_lds(AS1(qb + ((size_t)((c2 * 64 + rr) * 4 + b)) * 1024 + h * 128 + kc2 * 8),
                                       AS3(Qs[buf] + ch * 8), 16, 0, 0);
    }
  };

  STAGE(0, 0);
  asm volatile("s_waitcnt vmcnt(0)" ::: "memory");
  __builtin_amdgcn_s_barrier();

  for (int c = 0; c < NC; ++c) {
    const int cur = c & 1, nxt = cur ^ 1;
    const size_t pcb = ((size_t)bh * NC + c) * 4096;
    const h8 aP0 = *(const h8*)(pbuf + pcb + arow * 64 + koff);
    const h8 aP1 = *(const h8*)(pbuf + pcb + arow * 64 + 32 + koff);
    const size_t ucb = ((size_t)bh * NC + c) * 8192;
    const h4 u0 = *(const h4*)(utbuf + ucb + (size_t)(g * 16 + l15) * 64 + wv * 16 + l4 * 4);
    asm volatile("s_waitcnt vmcnt(3)" ::: "memory");
    asm volatile("s_waitcnt lgkmcnt(0)" ::: "memory");
    __builtin_amdgcn_s_barrier();
    if (c + 1 < NC) STAGE(c + 1, nxt);

    f4 accR = {}, accO = {};
    __builtin_amdgcn_s_setprio(1);
#pragma unroll
    for (int kc = 0; kc < 4; ++kc) {
      const int c4 = kc * 4 + l4;
      const h8 aW = *(const h8*)(Ws[cur] + arow * 128 + swz16(arow, c4) * 8);
      const h8 aQ = *(const h8*)(Qs[cur] + arow * 128 + swz16(arow, c4) * 8);
      const h8 bM = *(const h8*)(Ms + l15 * 136 + kc * 32 + koff);
      accR = __builtin_amdgcn_mfma_f32_16x16x32_f16(aW, bM, accR, 0, 0, 0);
      accO = __builtin_amdgcn_mfma_f32_16x16x32_f16(aQ, bM, accO, 0, 0, 0);
    }
    __builtin_amdgcn_s_setprio(0);
    if (c + 1 < NC) asm volatile("s_waitcnt vmcnt(12)" ::: "memory");
    else            asm volatile("s_waitcnt vmcnt(0)" ::: "memory");
    {
      h4 rw;
#pragma unroll
      for (int q = 0; q < 4; ++q) {
        const float rv = (float)u0[q] - accR[q];
        rw[q] = (f16)rv;
      }
      *(h4*)(Rt + l15 * 72 + wv * 16 + l4 * 4) = rw;
    }
    asm volatile("s_waitcnt lgkmcnt(0)" ::: "memory");
    __builtin_amdgcn_s_barrier();

#pragma unroll
    for (int kc = 0; kc < 2; ++kc) {
      const h8 aP = kc ? aP1 : aP0;
      const h8 bR = *(const h8*)(Rt + l15 * 72 + kc * 32 + koff);
      accO = __builtin_amdgcn_mfma_f32_16x16x32_f16(aP, bR, accO, 0, 0, 0);
    }
#pragma unroll
    for (int q = 0; q < 4; ++q) {
      const int i = wv * 16 + l4 * 4 + q;
      obuf[((size_t)(c * 64 + i) * Bb_ + b) * Dd + h * 128 + g * 16 + l15] = (f16)accO[q];
    }

#pragma unroll
    for (int kc = 0; kc < 2; ++kc) {
      const h8 aR0 = *(const h8*)(Rt + l15 * 72 + kc * 32 + koff);
#pragma unroll
      for (int cf = 0; cf < 2; ++cf) {
        const int kcol = wv * 32 + cf * 16 + l15;
        const int c2 = kc * 4 + l4;
        const h8 bKv = *(const h8*)(Kts[cur] + kcol * 64 + (c2 ^ (kcol & 7)) * 8);
        macc2[cf] = __builtin_amdgcn_mfma_f32_16x16x32_f16(aR0, bKv, macc2[cf], 0, 0, 0);
      }
    }
#pragma unroll
    for (int cf = 0; cf < 2; ++cf)
#pragma unroll
      for (int q = 0; q < 4; ++q) {
        const int cr = l4 * 4 + q;
        const int kcol = wv * 32 + cf * 16 + l15;
        Ms[cr * 136 + kcol] = (f16)macc2[cf][q];
      }
  }
}

// ---------------------------------------------------------------------------
extern "C" void kernel_launch(void* const* d_in, const int* in_sizes, int n_in,
                              void* d_out, int out_size, void* d_ws, size_t ws_size,
                              hipStream_t stream) {
  (void)in_sizes; (void)n_in;
  const float* input = (const float*)d_in[0];
  const float* Wq = (const float*)d_in[1];
  const float* Wk = (const float*)d_in[2];
  const float* Wv = (const float*)d_in[3];
  const float* Wb = (const float*)d_in[4];
  const float* Wo = (const float*)d_in[5];
  const float* onw = (const float*)d_in[6];
  const float* n1w = (const float*)d_in[7];
  const float* n2w = (const float*)d_in[8];
  const float* Wg = (const float*)d_in[9];
  const float* Wd = (const float*)d_in[10];
  const float* fnw = (const float*)d_in[11];

  char* ws = (char*)d_ws;
  size_t off = 0;
  auto alloc = [&](size_t bytes) { void* p = ws + off; off += (bytes + 255) & ~(size_t)255; return p; };
  const size_t RD = 8192ull * 1024ull;
  f16*  x     = (f16*)alloc(RD * 2);
  f16*  qb    = (f16*)alloc(RD * 2);
  f16*  kbuf  = (f16*)alloc(RD * 2);
  f16*  vbuf  = (f16*)alloc(RD * 2);
  float* beta = (float*)alloc(8192ull * 8 * 4);
  float* rs   = (float*)alloc(8192ull * 4);
  float* Wb2  = (float*)alloc(1024ull * 8 * 4);
  f16*  wbuf  = (f16*)alloc(RD * 2);
  f16*  utbuf = (f16*)alloc(RD * 2);
  f16*  ktbuf = (f16*)alloc(RD * 2);
  f16*  pbuf  = (f16*)alloc(32ull * 32 * 64 * 64 * 2);
  char* arena = (char*)alloc(3 * RD * 2);
  f16*  WqkvT = (f16*)alloc(3072ull * 1024 * 2);
  f16*  WoT   = (f16*)alloc(1024ull * 1024 * 2);
  f16*  WgT   = (f16*)alloc(5632ull * 1024 * 2);
  f16*  WdT   = (f16*)alloc(1024ull * 2816 * 2);
  if (off > ws_size) {
    fill_k<<<(out_size + 255) / 256, 256, 0, stream>>>((float*)d_out, out_size, 1.0e6f);
    return;
  }
  f16* obuf = (f16*)arena;
  f16* my = qb;     // qb/kbuf/vbuf dead by the MLP
  f16* ob = wbuf;   // wbuf dead after phaseB

  cvt_k<<<4096, 256, 0, stream>>>(input, x);

  for (int l = 0; l < 2; ++l) {
    const size_t o2 = (size_t)l * 1024 * 1024;
    transpose_k<1><<<dim3(32, 32), 256, 0, stream>>>(Wq + o2, n1w + l * 1024, WqkvT, 1024, 1024);
    transpose_k<1><<<dim3(32, 32), 256, 0, stream>>>(Wk + o2, n1w + l * 1024, WqkvT + 1024ull * 1024, 1024, 1024);
    transpose_k<1><<<dim3(32, 32), 256, 0, stream>>>(Wv + o2, n1w + l * 1024, WqkvT + 2048ull * 1024, 1024, 1024);
    transpose_k<0><<<dim3(32, 32), 256, 0, stream>>>(Wo + o2, nullptr, WoT, 1024, 1024);
    transpose_k<1><<<dim3(176, 32), 256, 0, stream>>>(Wg + (size_t)l * 1024 * 5632, n2w + l * 1024, WgT, 1024, 5632);
    transpose_k<0><<<dim3(32, 88), 256, 0, stream>>>(Wd + (size_t)l * 2816 * 1024, nullptr, WdT, 2816, 1024);
    bweight_k<<<32, 256, 0, stream>>>(Wb + (size_t)l * 1024 * 8, n1w + l * 1024, Wb2);

    rowscale_k<<<2048, 256, 0, stream>>>(x, rs);
    gemmQKV<<<32 * 24, 512, 0, stream>>>(x, WqkvT, rs, qb, kbuf, vbuf, 1024, 24);
    beta_k<<<2048, 256, 0, stream>>>(x, Wb2, rs, beta);
    phaseA<<<1024, 256, 0, stream>>>(kbuf, qb, vbuf, beta, wbuf, utbuf, pbuf, ktbuf);
    phaseB<<<256, 256, 0, stream>>>(qb, ktbuf, wbuf, utbuf, pbuf, obuf);
    onorm_k<<<8192, 256, 0, stream>>>(obuf, onw + l * 128, ob);
    gemm2<1, 0><<<32 * 8, 512, 0, stream>>>(ob, WoT, x, nullptr, 8192, 1024, 1024, 8);

    rowscale_k<<<2048, 256, 0, stream>>>(x, rs);
    gemmGLU<<<32 * 22, 512, 0, stream>>>(x, WgT, rs, my, 1024, 22);
    gemm2<1, 0><<<32 * 8, 512, 0, stream>>>(my, WdT, x, nullptr, 8192, 1024, 2816, 8);
  }
  rmsnorm_f<<<8192, 256, 0, stream>>>(x, fnw, (float*)d_out);
}

// Round 13
// 923.575 us; speedup vs baseline: 1.0509x; 1.0509x over previous
//
#include <hip/hip_runtime.h>
#include <hip/hip_bf16.h>
#include <cstdint>

// DeltaNet forward, MI355X. Round 13: revert GEMMs to R11 (R12 single-buffer
// regressed); batch weight-prep across layers (z=2); fuse rowscale+beta.

typedef _Float16 f16;
typedef __attribute__((ext_vector_type(8))) _Float16 h8;
typedef __attribute__((ext_vector_type(4))) _Float16 h4;
typedef __attribute__((ext_vector_type(4))) float f4;

#define DEV __device__ __forceinline__

static constexpr int Bb_ = 4;
static constexpr int Hh  = 8;
static constexpr int Dd  = 1024;
static constexpr int Tt  = 2048;
static constexpr int NC  = 32;

DEV float siluf(float x) { return x / (1.f + expf(-x)); }
DEV int swz16(int row, int c) { return (c & 8) | ((c & 7) ^ (row & 7)); }

#define AS1(p) ((const __attribute__((address_space(1))) void*)(uintptr_t)(p))
#define AS3(p) ((__attribute__((address_space(3))) void*)(uint32_t)(uintptr_t)(p))

DEV h8 rd_sw(const f16* T, int row, int chunk) {
  return *(const h8*)(T + (((row << 3) | (chunk ^ (row & 7))) * 8));
}

// ================= 2-phase GEMM (R11): C[M,N] op= A[M,K]*Bt[N,K]^T, BN=128 ==
template<int EPI, int SC>  // EPI 1: f16 += ; 2: f16 store. SC: row-scale
__global__ __launch_bounds__(512, 2) void gemm2(const f16* __restrict__ A, const f16* __restrict__ Bt,
                                                void* __restrict__ C, const float* __restrict__ rs,
                                                int M, int N, int K, int gx) {
  __shared__ __align__(16) f16 ldsA[2][16384];
  __shared__ __align__(16) f16 ldsB[2][8192];
  const int tid = threadIdx.x, lane = tid & 63, w = tid >> 6;
  const int l15 = lane & 15, l4 = lane >> 4;
  const int wr = w >> 2, wc = w & 3;
  const int nwg = gridDim.x;
  int flat = blockIdx.x;
  if ((nwg & 7) == 0) flat = (flat & 7) * (nwg >> 3) + (flat >> 3);
  const int bx = flat % gx, by = flat / gx;

  const f16* Ab = A + (size_t)by * 256 * K;
  const f16* Bb = Bt + (size_t)bx * 128 * K;
  const int NT = K >> 6;
  f4 acc[8][2] = {};

  const int r0 = tid >> 3;
  const size_t soff0 = (size_t)r0 * K + (size_t)(((tid & 7) ^ (r0 & 7)) * 8);
  const size_t soff1 = soff0 + (size_t)64 * K;
  const int dof = tid * 8;
  auto STG = [&](const f16* base, f16* dst) {
    __builtin_amdgcn_global_load_lds(AS1(base + soff0), AS3(dst + dof), 16, 0, 0);
    __builtin_amdgcn_global_load_lds(AS1(base + soff1), AS3(dst + 4096 + dof), 16, 0, 0);
  };

  STG(Bb, ldsB[0]);
  STG(Ab, ldsA[0]);
  STG(Ab + (size_t)128 * K, ldsA[0] + 8192);
  if (NT > 1) {
    STG(Bb + 64, ldsB[1]);
    asm volatile("s_waitcnt vmcnt(2)");
  } else {
    asm volatile("s_waitcnt vmcnt(0)");
  }
  __builtin_amdgcn_s_barrier();

  for (int t = 0; t < NT; ++t) {
    const int cur = t & 1, nxt = cur ^ 1;
    const f16* cA = ldsA[cur];
    const f16* cB = ldsB[cur];
    h8 b[2][2], aX[2][2], aY[2][2];
#pragma unroll
    for (int cf = 0; cf < 2; ++cf)
#pragma unroll
      for (int ks = 0; ks < 2; ++ks)
        b[cf][ks] = rd_sw(cB, wc * 32 + cf * 16 + l15, ks * 4 + l4);
#pragma unroll
    for (int fr = 0; fr < 2; ++fr)
#pragma unroll
      for (int ks = 0; ks < 2; ++ks)
        aX[fr][ks] = rd_sw(cA, wr * 128 + fr * 16 + l15, ks * 4 + l4);
    if (t + 1 < NT) { STG(Ab + (t + 1) * 64, ldsA[nxt]); STG(Ab + (size_t)128 * K + (t + 1) * 64, ldsA[nxt] + 8192); }
    __builtin_amdgcn_s_setprio(1);
#pragma unroll
    for (int fr = 0; fr < 2; ++fr)
#pragma unroll
      for (int cf = 0; cf < 2; ++cf)
#pragma unroll
        for (int ks = 0; ks < 2; ++ks)
          acc[fr][cf] = __builtin_amdgcn_mfma_f32_16x16x32_f16(aX[fr][ks], b[cf][ks], acc[fr][cf], 0, 0, 0);
#pragma unroll
    for (int fr = 0; fr < 2; ++fr)
#pragma unroll
      for (int ks = 0; ks < 2; ++ks)
        aY[fr][ks] = rd_sw(cA, wr * 128 + 32 + fr * 16 + l15, ks * 4 + l4);
#pragma unroll
    for (int fr = 0; fr < 2; ++fr)
#pragma unroll
      for (int cf = 0; cf < 2; ++cf)
#pragma unroll
        for (int ks = 0; ks < 2; ++ks)
          acc[2 + fr][cf] = __builtin_amdgcn_mfma_f32_16x16x32_f16(aY[fr][ks], b[cf][ks], acc[2 + fr][cf], 0, 0, 0);
    __builtin_amdgcn_s_setprio(0);
    __builtin_amdgcn_s_barrier();
#pragma unroll
    for (int fr = 0; fr < 2; ++fr)
#pragma unroll
      for (int ks = 0; ks < 2; ++ks)
        aX[fr][ks] = rd_sw(cA, wr * 128 + 64 + fr * 16 + l15, ks * 4 + l4);
    if (t + 2 < NT) STG(Bb + (t + 2) * 64, ldsB[cur]);
    __builtin_amdgcn_s_setprio(1);
#pragma unroll
    for (int fr = 0; fr < 2; ++fr)
#pragma unroll
      for (int cf = 0; cf < 2; ++cf)
#pragma unroll
        for (int ks = 0; ks < 2; ++ks)
          acc[4 + fr][cf] = __builtin_amdgcn_mfma_f32_16x16x32_f16(aX[fr][ks], b[cf][ks], acc[4 + fr][cf], 0, 0, 0);
#pragma unroll
    for (int fr = 0; fr < 2; ++fr)
#pragma unroll
      for (int ks = 0; ks < 2; ++ks)
        aY[fr][ks] = rd_sw(cA, wr * 128 + 96 + fr * 16 + l15, ks * 4 + l4);
#pragma unroll
    for (int fr = 0; fr < 2; ++fr)
#pragma unroll
      for (int cf = 0; cf < 2; ++cf)
#pragma unroll
        for (int ks = 0; ks < 2; ++ks)
          acc[6 + fr][cf] = __builtin_amdgcn_mfma_f32_16x16x32_f16(aY[fr][ks], b[cf][ks], acc[6 + fr][cf], 0, 0, 0);
    __builtin_amdgcn_s_setprio(0);
    if (t + 2 < NT)      asm volatile("s_waitcnt vmcnt(2)" ::: "memory");
    else if (t + 1 < NT) asm volatile("s_waitcnt vmcnt(0)" ::: "memory");
    __builtin_amdgcn_s_barrier();
  }

#pragma unroll
  for (int fr = 0; fr < 8; ++fr) {
#pragma unroll
    for (int cf = 0; cf < 2; ++cf) {
      const int row0 = by * 256 + wr * 128 + fr * 16 + l4 * 4;
      const int col = bx * 128 + wc * 32 + cf * 16 + l15;
#pragma unroll
      for (int q = 0; q < 4; ++q) {
        const size_t idx = (size_t)(row0 + q) * N + col;
        float v = acc[fr][cf][q];
        if (SC) v *= rs[row0 + q];
        if (EPI == 1) ((f16*)C)[idx] = (f16)((float)((f16*)C)[idx] + v);
        if (EPI == 2) ((f16*)C)[idx] = (f16)v;
      }
    }
  }
}

// ============ QKV GEMM (R11) with fused silu+l2norm epilogue ===============
__global__ __launch_bounds__(512, 2) void gemmQKV(const f16* __restrict__ A, const f16* __restrict__ Bt,
                                                  const float* __restrict__ rs, f16* __restrict__ qb,
                                                  f16* __restrict__ kb, f16* __restrict__ vb,
                                                  int K, int gx) {
  __shared__ __align__(16) f16 ldsA[2][16384];
  __shared__ __align__(16) f16 ldsB[2][8192];
  __shared__ float ps[4][256];
  const int tid = threadIdx.x, lane = tid & 63, w = tid >> 6;
  const int l15 = lane & 15, l4 = lane >> 4;
  const int wr = w >> 2, wc = w & 3;
  const int nwg = gridDim.x;
  int flat = blockIdx.x;
  if ((nwg & 7) == 0) flat = (flat & 7) * (nwg >> 3) + (flat >> 3);
  const int bx = flat % gx, by = flat / gx;

  const f16* Ab = A + (size_t)by * 256 * K;
  const f16* Bb = Bt + (size_t)bx * 128 * K;
  const int NT = K >> 6;
  f4 acc[8][2] = {};

  const int r0 = tid >> 3;
  const size_t soff0 = (size_t)r0 * K + (size_t)(((tid & 7) ^ (r0 & 7)) * 8);
  const size_t soff1 = soff0 + (size_t)64 * K;
  const int dof = tid * 8;
  auto STG = [&](const f16* base, f16* dst) {
    __builtin_amdgcn_global_load_lds(AS1(base + soff0), AS3(dst + dof), 16, 0, 0);
    __builtin_amdgcn_global_load_lds(AS1(base + soff1), AS3(dst + 4096 + dof), 16, 0, 0);
  };

  STG(Bb, ldsB[0]);
  STG(Ab, ldsA[0]);
  STG(Ab + (size_t)128 * K, ldsA[0] + 8192);
  if (NT > 1) {
    STG(Bb + 64, ldsB[1]);
    asm volatile("s_waitcnt vmcnt(2)");
  } else {
    asm volatile("s_waitcnt vmcnt(0)");
  }
  __builtin_amdgcn_s_barrier();

  for (int t = 0; t < NT; ++t) {
    const int cur = t & 1, nxt = cur ^ 1;
    const f16* cA = ldsA[cur];
    const f16* cB = ldsB[cur];
    h8 b[2][2], aX[2][2], aY[2][2];
#pragma unroll
    for (int cf = 0; cf < 2; ++cf)
#pragma unroll
      for (int ks = 0; ks < 2; ++ks)
        b[cf][ks] = rd_sw(cB, wc * 32 + cf * 16 + l15, ks * 4 + l4);
#pragma unroll
    for (int fr = 0; fr < 2; ++fr)
#pragma unroll
      for (int ks = 0; ks < 2; ++ks)
        aX[fr][ks] = rd_sw(cA, wr * 128 + fr * 16 + l15, ks * 4 + l4);
    if (t + 1 < NT) { STG(Ab + (t + 1) * 64, ldsA[nxt]); STG(Ab + (size_t)128 * K + (t + 1) * 64, ldsA[nxt] + 8192); }
    __builtin_amdgcn_s_setprio(1);
#pragma unroll
    for (int fr = 0; fr < 2; ++fr)
#pragma unroll
      for (int cf = 0; cf < 2; ++cf)
#pragma unroll
        for (int ks = 0; ks < 2; ++ks)
          acc[fr][cf] = __builtin_amdgcn_mfma_f32_16x16x32_f16(aX[fr][ks], b[cf][ks], acc[fr][cf], 0, 0, 0);
#pragma unroll
    for (int fr = 0; fr < 2; ++fr)
#pragma unroll
      for (int ks = 0; ks < 2; ++ks)
        aY[fr][ks] = rd_sw(cA, wr * 128 + 32 + fr * 16 + l15, ks * 4 + l4);
#pragma unroll
    for (int fr = 0; fr < 2; ++fr)
#pragma unroll
      for (int cf = 0; cf < 2; ++cf)
#pragma unroll
        for (int ks = 0; ks < 2; ++ks)
          acc[2 + fr][cf] = __builtin_amdgcn_mfma_f32_16x16x32_f16(aY[fr][ks], b[cf][ks], acc[2 + fr][cf], 0, 0, 0);
    __builtin_amdgcn_s_setprio(0);
    __builtin_amdgcn_s_barrier();
#pragma unroll
    for (int fr = 0; fr < 2; ++fr)
#pragma unroll
      for (int ks = 0; ks < 2; ++ks)
        aX[fr][ks] = rd_sw(cA, wr * 128 + 64 + fr * 16 + l15, ks * 4 + l4);
    if (t + 2 < NT) STG(Bb + (t + 2) * 64, ldsB[cur]);
    __builtin_amdgcn_s_setprio(1);
#pragma unroll
    for (int fr = 0; fr < 2; ++fr)
#pragma unroll
      for (int cf = 0; cf < 2; ++cf)
#pragma unroll
        for (int ks = 0; ks < 2; ++ks)
          acc[4 + fr][cf] = __builtin_amdgcn_mfma_f32_16x16x32_f16(aX[fr][ks], b[cf][ks], acc[4 + fr][cf], 0, 0, 0);
#pragma unroll
    for (int fr = 0; fr < 2; ++fr)
#pragma unroll
      for (int ks = 0; ks < 2; ++ks)
        aY[fr][ks] = rd_sw(cA, wr * 128 + 96 + fr * 16 + l15, ks * 4 + l4);
#pragma unroll
    for (int fr = 0; fr < 2; ++fr)
#pragma unroll
      for (int cf = 0; cf < 2; ++cf)
#pragma unroll
        for (int ks = 0; ks < 2; ++ks)
          acc[6 + fr][cf] = __builtin_amdgcn_mfma_f32_16x16x32_f16(aY[fr][ks], b[cf][ks], acc[6 + fr][cf], 0, 0, 0);
    __builtin_amdgcn_s_setprio(0);
    if (t + 2 < NT)      asm volatile("s_waitcnt vmcnt(2)" ::: "memory");
    else if (t + 1 < NT) asm volatile("s_waitcnt vmcnt(0)" ::: "memory");
    __builtin_amdgcn_s_barrier();
  }

#pragma unroll
  for (int fr = 0; fr < 8; ++fr)
#pragma unroll
    for (int q = 0; q < 4; ++q) {
      const int grow = by * 256 + wr * 128 + fr * 16 + l4 * 4 + q;
      const float s = rs[grow];
#pragma unroll
      for (int cf = 0; cf < 2; ++cf)
        acc[fr][cf][q] = siluf(s * acc[fr][cf][q]);
    }
  if (bx < 16) {
    float sq[8][4];
#pragma unroll
    for (int fr = 0; fr < 8; ++fr)
#pragma unroll
      for (int q = 0; q < 4; ++q) {
        float v = acc[fr][0][q] * acc[fr][0][q] + acc[fr][1][q] * acc[fr][1][q];
#pragma unroll
        for (int m = 1; m < 16; m <<= 1) v += __shfl_xor(v, m);
        sq[fr][q] = v;
      }
    if (l15 == 0) {
#pragma unroll
      for (int fr = 0; fr < 8; ++fr)
#pragma unroll
        for (int q = 0; q < 4; ++q)
          ps[wc][wr * 128 + fr * 16 + l4 * 4 + q] = sq[fr][q];
    }
    __syncthreads();
#pragma unroll
    for (int fr = 0; fr < 8; ++fr)
#pragma unroll
      for (int q = 0; q < 4; ++q) {
        const int rl = wr * 128 + fr * 16 + l4 * 4 + q;
        const float sc = rsqrtf(ps[0][rl] + ps[1][rl] + ps[2][rl] + ps[3][rl] + 1e-6f);
#pragma unroll
        for (int cf = 0; cf < 2; ++cf) acc[fr][cf][q] *= sc;
      }
  }
  f16* dst = (bx < 8) ? qb : ((bx < 16) ? kb : vb);
  const int head = bx & 7;
#pragma unroll
  for (int fr = 0; fr < 8; ++fr)
#pragma unroll
    for (int cf = 0; cf < 2; ++cf)
#pragma unroll
      for (int q = 0; q < 4; ++q) {
        const int grow = by * 256 + wr * 128 + fr * 16 + l4 * 4 + q;
        const int i = (grow >> 2) & 63;
        const int dh = wc * 32 + cf * 16 + l15;
        dst[(size_t)grow * 1024 + head * 128 + swz16(i, dh >> 3) * 8 + (dh & 7)] = (f16)acc[fr][cf][q];
      }
}

// ============ fused GLU GEMM (R11, 2-phase dbuf) ===========================
__global__ __launch_bounds__(512, 2) void gemmGLU(const f16* __restrict__ A, const f16* __restrict__ WgT,
                                                  const float* __restrict__ rs, f16* __restrict__ my,
                                                  int K, int gx) {
  __shared__ __align__(16) f16 ldsA[2][16384];
  __shared__ __align__(16) f16 ldsG[2][8192];
  __shared__ __align__(16) f16 ldsY[2][8192];
  const int tid = threadIdx.x, lane = tid & 63, w = tid >> 6;
  const int l15 = lane & 15, l4 = lane >> 4;
  const int wr = w >> 2, wc = w & 3;
  const int nwg = gridDim.x;
  int flat = blockIdx.x;
  if ((nwg & 7) == 0) flat = (flat & 7) * (nwg >> 3) + (flat >> 3);
  const int bx = flat % gx, by = flat / gx;

  const f16* Ab = A + (size_t)by * 256 * K;
  const f16* Gb = WgT + (size_t)bx * 128 * K;
  const f16* Yb = WgT + (size_t)(2816 + bx * 128) * K;
  const int NT = K >> 6;
  f4 accG[8][2] = {}, accY[8][2] = {};

  const int r0 = tid >> 3;
  const size_t soff0 = (size_t)r0 * K + (size_t)(((tid & 7) ^ (r0 & 7)) * 8);
  const size_t soff1 = soff0 + (size_t)64 * K;
  const int dof = tid * 8;
  auto STG = [&](const f16* base, f16* dst) {
    __builtin_amdgcn_global_load_lds(AS1(base + soff0), AS3(dst + dof), 16, 0, 0);
    __builtin_amdgcn_global_load_lds(AS1(base + soff1), AS3(dst + 4096 + dof), 16, 0, 0);
  };

  STG(Gb, ldsG[0]);
  STG(Yb, ldsY[0]);
  STG(Ab, ldsA[0]);
  STG(Ab + (size_t)128 * K, ldsA[0] + 8192);
  if (NT > 1) {
    STG(Gb + 64, ldsG[1]);
    STG(Yb + 64, ldsY[1]);
    asm volatile("s_waitcnt vmcnt(4)");
  } else {
    asm volatile("s_waitcnt vmcnt(0)");
  }
  __builtin_amdgcn_s_barrier();

  for (int t = 0; t < NT; ++t) {
    const int cur = t & 1, nxt = cur ^ 1;
    const f16* cA = ldsA[cur];
    h8 bg[2][2], byv[2][2], aX[2][2], aY[2][2];
#pragma unroll
    for (int cf = 0; cf < 2; ++cf)
#pragma unroll
      for (int ks = 0; ks < 2; ++ks) {
        bg[cf][ks] = rd_sw(ldsG[cur], wc * 32 + cf * 16 + l15, ks * 4 + l4);
        byv[cf][ks] = rd_sw(ldsY[cur], wc * 32 + cf * 16 + l15, ks * 4 + l4);
      }
#pragma unroll
    for (int fr = 0; fr < 2; ++fr)
#pragma unroll
      for (int ks = 0; ks < 2; ++ks)
        aX[fr][ks] = rd_sw(cA, wr * 128 + fr * 16 + l15, ks * 4 + l4);
    if (t + 1 < NT) { STG(Ab + (t + 1) * 64, ldsA[nxt]); STG(Ab + (size_t)128 * K + (t + 1) * 64, ldsA[nxt] + 8192); }
    __builtin_amdgcn_s_setprio(1);
#pragma unroll
    for (int fr = 0; fr < 2; ++fr)
#pragma unroll
      for (int cf = 0; cf < 2; ++cf)
#pragma unroll
        for (int ks = 0; ks < 2; ++ks) {
          accG[fr][cf] = __builtin_amdgcn_mfma_f32_16x16x32_f16(aX[fr][ks], bg[cf][ks], accG[fr][cf], 0, 0, 0);
          accY[fr][cf] = __builtin_amdgcn_mfma_f32_16x16x32_f16(aX[fr][ks], byv[cf][ks], accY[fr][cf], 0, 0, 0);
        }
#pragma unroll
    for (int fr = 0; fr < 2; ++fr)
#pragma unroll
      for (int ks = 0; ks < 2; ++ks)
        aY[fr][ks] = rd_sw(cA, wr * 128 + 32 + fr * 16 + l15, ks * 4 + l4);
#pragma unroll
    for (int fr = 0; fr < 2; ++fr)
#pragma unroll
      for (int cf = 0; cf < 2; ++cf)
#pragma unroll
        for (int ks = 0; ks < 2; ++ks) {
          accG[2 + fr][cf] = __builtin_amdgcn_mfma_f32_16x16x32_f16(aY[fr][ks], bg[cf][ks], accG[2 + fr][cf], 0, 0, 0);
          accY[2 + fr][cf] = __builtin_amdgcn_mfma_f32_16x16x32_f16(aY[fr][ks], byv[cf][ks], accY[2 + fr][cf], 0, 0, 0);
        }
    __builtin_amdgcn_s_setprio(0);
    __builtin_amdgcn_s_barrier();
#pragma unroll
    for (int fr = 0; fr < 2; ++fr)
#pragma unroll
      for (int ks = 0; ks < 2; ++ks)
        aX[fr][ks] = rd_sw(cA, wr * 128 + 64 + fr * 16 + l15, ks * 4 + l4);
    if (t + 2 < NT) { STG(Gb + (t + 2) * 64, ldsG[cur]); STG(Yb + (t + 2) * 64, ldsY[cur]); }
    __builtin_amdgcn_s_setprio(1);
#pragma unroll
    for (int fr = 0; fr < 2; ++fr)
#pragma unroll
      for (int cf = 0; cf < 2; ++cf)
#pragma unroll
        for (int ks = 0; ks < 2; ++ks) {
          accG[4 + fr][cf] = __builtin_amdgcn_mfma_f32_16x16x32_f16(aX[fr][ks], bg[cf][ks], accG[4 + fr][cf], 0, 0, 0);
          accY[4 + fr][cf] = __builtin_amdgcn_mfma_f32_16x16x32_f16(aX[fr][ks], byv[cf][ks], accY[4 + fr][cf], 0, 0, 0);
        }
#pragma unroll
    for (int fr = 0; fr < 2; ++fr)
#pragma unroll
      for (int ks = 0; ks < 2; ++ks)
        aY[fr][ks] = rd_sw(cA, wr * 128 + 96 + fr * 16 + l15, ks * 4 + l4);
#pragma unroll
    for (int fr = 0; fr < 2; ++fr)
#pragma unroll
      for (int cf = 0; cf < 2; ++cf)
#pragma unroll
        for (int ks = 0; ks < 2; ++ks) {
          accG[6 + fr][cf] = __builtin_amdgcn_mfma_f32_16x16x32_f16(aY[fr][ks], bg[cf][ks], accG[6 + fr][cf], 0, 0, 0);
          accY[6 + fr][cf] = __builtin_amdgcn_mfma_f32_16x16x32_f16(aY[fr][ks], byv[cf][ks], accY[6 + fr][cf], 0, 0, 0);
        }
    __builtin_amdgcn_s_setprio(0);
    if (t + 2 < NT)      asm volatile("s_waitcnt vmcnt(4)" ::: "memory");
    else if (t + 1 < NT) asm volatile("s_waitcnt vmcnt(0)" ::: "memory");
    __builtin_amdgcn_s_barrier();
  }

#pragma unroll
  for (int fr = 0; fr < 8; ++fr) {
#pragma unroll
    for (int cf = 0; cf < 2; ++cf) {
      const int row0 = by * 256 + wr * 128 + fr * 16 + l4 * 4;
      const int col = bx * 128 + wc * 32 + cf * 16 + l15;
#pragma unroll
      for (int q = 0; q < 4; ++q) {
        const float s = rs[row0 + q];
        my[(size_t)(row0 + q) * 2816 + col] = (f16)(siluf(s * accG[fr][cf][q]) * (s * accY[fr][cf][q]));
      }
    }
  }
}

// ---------------- f32 -> f16 convert ---------------------------------------
__global__ __launch_bounds__(256) void cvt_k(const float* __restrict__ in, f16* __restrict__ out) {
  const size_t i = ((size_t)blockIdx.x * 256 + threadIdx.x) * 8;
  const float4 a = *(const float4*)(in + i);
  const float4 b = *(const float4*)(in + i + 4);
  h8 o = {(f16)a.x, (f16)a.y, (f16)a.z, (f16)a.w, (f16)b.x, (f16)b.y, (f16)b.z, (f16)b.w};
  *(h8*)(out + i) = o;
}

// ---------------- rowscale only (norm2) ------------------------------------
__global__ __launch_bounds__(256) void rowscale_k(const f16* __restrict__ x, float* __restrict__ rs) {
  const int tid = threadIdx.x, lane = tid & 63, wv = tid >> 6;
  const int r = blockIdx.x * 4 + wv;
  const f16* row = x + (size_t)r * 1024 + lane * 16;
  const h8 v0 = *(const h8*)(row);
  const h8 v1 = *(const h8*)(row + 8);
  float ss = 0.f;
#pragma unroll
  for (int e = 0; e < 8; ++e) {
    const float a = (float)v0[e], b = (float)v1[e];
    ss += a * a + b * b;
  }
#pragma unroll
  for (int m = 1; m < 64; m <<= 1) ss += __shfl_xor(ss, m);
  if (lane == 0) rs[r] = rsqrtf(ss * (1.f / 1024.f) + 1e-6f);
}

// -------- fused rowscale + beta (norm1): one pass over x -------------------
__global__ __launch_bounds__(256) void rsbeta_k(const f16* __restrict__ x, const float* __restrict__ Wb2,
                                                float* __restrict__ rs, float* __restrict__ beta) {
  const int tid = threadIdx.x, lane = tid & 63, wv = tid >> 6;
  const int r = blockIdx.x * 4 + wv;
  const f16* row = x + (size_t)r * 1024 + lane * 16;
  const h8 v0 = *(const h8*)(row);
  const h8 v1 = *(const h8*)(row + 8);
  const float* wb = Wb2 + (size_t)(lane * 16) * 8;
  float ss = 0.f;
  float acc[8] = {};
#pragma unroll
  for (int e = 0; e < 8; ++e) {
    const float x0 = (float)v0[e], x1 = (float)v1[e];
    ss += x0 * x0 + x1 * x1;
    const float4 w0a = *(const float4*)(wb + e * 8);
    const float4 w0b = *(const float4*)(wb + e * 8 + 4);
    const float4 w1a = *(const float4*)(wb + (e + 8) * 8);
    const float4 w1b = *(const float4*)(wb + (e + 8) * 8 + 4);
    acc[0] += x0 * w0a.x + x1 * w1a.x;  acc[1] += x0 * w0a.y + x1 * w1a.y;
    acc[2] += x0 * w0a.z + x1 * w1a.z;  acc[3] += x0 * w0a.w + x1 * w1a.w;
    acc[4] += x0 * w0b.x + x1 * w1b.x;  acc[5] += x0 * w0b.y + x1 * w1b.y;
    acc[6] += x0 * w0b.z + x1 * w1b.z;  acc[7] += x0 * w0b.w + x1 * w1b.w;
  }
#pragma unroll
  for (int m = 1; m < 64; m <<= 1) ss += __shfl_xor(ss, m);
#pragma unroll
  for (int j = 0; j < 8; ++j)
#pragma unroll
    for (int m = 1; m < 64; m <<= 1) acc[j] += __shfl_xor(acc[j], m);
  if (lane == 0) {
    const float s = rsqrtf(ss * (1.f / 1024.f) + 1e-6f);
    rs[r] = s;
#pragma unroll
    for (int j = 0; j < 8; ++j) beta[(size_t)r * 8 + j] = 2.f / (1.f + expf(-acc[j] * s));
  }
}

// ---------------- final RMSNorm (f16 in, f32 out) --------------------------
__global__ __launch_bounds__(256) void rmsnorm_f(const f16* __restrict__ x, const float* __restrict__ w,
                                                 float* __restrict__ out) {
  const int r = blockIdx.x, tid = threadIdx.x;
  const h4 xv = *(const h4*)(x + (size_t)r * 1024 + tid * 4);
  const float v0 = (float)xv[0], v1 = (float)xv[1], v2 = (float)xv[2], v3 = (float)xv[3];
  float ss = v0 * v0 + v1 * v1 + v2 * v2 + v3 * v3;
#pragma unroll
  for (int m = 1; m < 64; m <<= 1) ss += __shfl_xor(ss, m);
  __shared__ float red[4];
  if ((tid & 63) == 0) red[tid >> 6] = ss;
  __syncthreads();
  const float scale = rsqrtf((red[0] + red[1] + red[2] + red[3]) * (1.f / 1024.f) + 1e-6f);
  const float4 w4 = *(const float4*)(w + tid * 4);
  *(float4*)(out + (size_t)r * 1024 + tid * 4) =
      make_float4(v0 * scale * w4.x, v1 * scale * w4.y, v2 * scale * w4.z, v3 * scale * w4.w);
}

// ---------------- per-head RMSNorm -----------------------------------------
__global__ __launch_bounds__(256) void onorm_k(const f16* __restrict__ o, const float* __restrict__ w,
                                               f16* __restrict__ ob) {
  const int r = blockIdx.x, tid = threadIdx.x;
  const int head = tid >> 5, l32 = tid & 31;
  const size_t base = (size_t)r * 1024 + head * 128 + l32 * 4;
  const h4 xv = *(const h4*)(o + base);
  const float v0 = (float)xv[0], v1 = (float)xv[1], v2 = (float)xv[2], v3 = (float)xv[3];
  float ss = v0 * v0 + v1 * v1 + v2 * v2 + v3 * v3;
#pragma unroll
  for (int m = 1; m <= 16; m <<= 1) ss += __shfl_xor(ss, m);
  const float sc = rsqrtf(ss * (1.f / 128.f) + 1e-6f);
  const float4 w4 = *(const float4*)(w + l32 * 4);
  h4 out = {(f16)(v0 * sc * w4.x), (f16)(v1 * sc * w4.y), (f16)(v2 * sc * w4.z), (f16)(v3 * sc * w4.w)};
  *(h4*)(ob + base) = out;
}

// ------ W[K][N] f32 -> Wt[N][K] f16 (both layers via blockIdx.z) -----------
template<int FOLD>
__global__ __launch_bounds__(256) void transpose_k(const float* __restrict__ W, const float* __restrict__ rw,
                                                   f16* __restrict__ Wt, int K, int N,
                                                   size_t inLS, size_t outLS) {
  __shared__ float tile[32][33];
  const int l = blockIdx.z;
  W += (size_t)l * inLS;
  Wt += (size_t)l * outLS;
  if (FOLD) rw += (size_t)l * 1024;
  const int n0 = blockIdx.x * 32, k0 = blockIdx.y * 32;
  const int tx = threadIdx.x & 31, ty = threadIdx.x >> 5;
#pragma unroll
  for (int i = 0; i < 32; i += 8) {
    float v = W[(size_t)(k0 + ty + i) * N + n0 + tx];
    if (FOLD) v *= rw[k0 + ty + i];
    tile[ty + i][tx] = v;
  }
  __syncthreads();
#pragma unroll
  for (int i = 0; i < 32; i += 8) Wt[(size_t)(n0 + ty + i) * K + k0 + tx] = (f16)tile[tx][ty + i];
}

// ---------------- Wb' = diag(n1w) Wb (both layers) -------------------------
__global__ __launch_bounds__(256) void bweight_k(const float* __restrict__ Wb, const float* __restrict__ n1w,
                                                 float* __restrict__ Wb2) {
  const int idx = blockIdx.x * 256 + threadIdx.x;  // 0..16383
  const int l = idx >> 13, e = idx & 8191;
  Wb2[idx] = Wb[idx] * n1w[l * 1024 + (e >> 3)];
}

__global__ void fill_k(float* p, int n, float v) {
  const int i = blockIdx.x * 256 + threadIdx.x;
  if (i < n) p[i] = v;
}

// ---------------- Phase A: WY transform ------------------------------------
DEV f4 mm16(const f16* A, int as, const f16* B, f4 c, int l15, int l4) {
  h4 a = *(const h4*)(A + l15 * as + l4 * 4);
  h4 b = *(const h4*)(B + l15 * 20 + l4 * 4);
  return __builtin_amdgcn_mfma_f32_16x16x16f16(a, b, c, 0, 0, 0);
}
DEV void wr_T(f16* slot, f4 acc, int l15, int l4, float sgn) {
  h4 v = {(f16)(sgn * acc[0]), (f16)(sgn * acc[1]), (f16)(sgn * acc[2]), (f16)(sgn * acc[3])};
  *(h4*)(slot + l15 * 20 + l4 * 4) = v;
}
DEV void wr_Tb(f16* Tb, int bi, int bj, f4 acc, const float* betas, int l15, int l4, float sgn) {
  const float bc = betas[bj * 16 + l15];
#pragma unroll
  for (int q = 0; q < 4; ++q)
    Tb[(bi * 16 + l4 * 4 + q) * 72 + bj * 16 + l15] = (f16)(sgn * acc[q] * bc);
}

__global__ __launch_bounds__(256) void phaseA(const f16* __restrict__ kb, const f16* __restrict__ qb,
                                              const f16* __restrict__ vb, const float* __restrict__ beta,
                                              f16* __restrict__ wbuf, f16* __restrict__ utbuf,
                                              f16* __restrict__ pbuf, f16* __restrict__ ktbuf) {
  const int blk = blockIdx.x;
  const int c = blk >> 5, bh = blk & 31;
  const int b = bh >> 3, h = bh & 7;
  const int tid = threadIdx.x, lane = tid & 63, wv = tid >> 6;
  const int l15 = lane & 15, l4 = lane >> 4;

  __shared__ __align__(16) f16 Ks[64 * 128];
  __shared__ __align__(16) f16 QVs[64 * 128];
  __shared__ __align__(16) f16 Abuf[64 * 68];
  __shared__ __align__(16) f16 Dr[4][16 * 20];
  __shared__ __align__(16) f16 Dt[4][16 * 20];
  __shared__ __align__(16) f16 Tp[3][16 * 20];
  __shared__ __align__(16) f16 Xp[3][16 * 20];
  __shared__ __align__(16) f16 Tb[64 * 72];
  __shared__ float betas[64];

  const size_t rowstr = (size_t)Bb_ * Dd;
  const size_t gbase = ((size_t)(c * 64) * Bb_ + b) * Dd + h * 128;

#pragma unroll
  for (int i = 0; i < 4; ++i) {
    const int ch = tid + i * 256;
    const int rr = ch >> 4, kc = ch & 15;
    *(h8*)(Ks + ch * 8) = *(const h8*)(kb + gbase + (size_t)rr * rowstr + kc * 8);
    *(h8*)(QVs + ch * 8) = *(const h8*)(qb + gbase + (size_t)rr * rowstr + kc * 8);
  }
  for (int i = tid; i < 64 * 72; i += 256) Tb[i] = (f16)0.f;
  if (tid < 64) betas[tid] = beta[((size_t)(c * 64 + tid) * Bb_ + b) * Hh + h];
  __syncthreads();

  f4 accS[4] = {}, accP[4] = {};
  const int arow = wv * 16 + l15;
#pragma unroll
  for (int kc = 0; kc < 4; ++kc) {
    const int c4 = kc * 4 + l4;
    const h8 aK = *(const h8*)(Ks + arow * 128 + swz16(arow, c4) * 8);
    const h8 aQ = *(const h8*)(QVs + arow * 128 + swz16(arow, c4) * 8);
#pragma unroll
    for (int f = 0; f < 4; ++f) {
      const int brow = f * 16 + l15;
      const h8 bK = *(const h8*)(Ks + brow * 128 + swz16(brow, c4) * 8);
      accS[f] = __builtin_amdgcn_mfma_f32_16x16x32_f16(aK, bK, accS[f], 0, 0, 0);
      accP[f] = __builtin_amdgcn_mfma_f32_16x16x32_f16(aQ, bK, accP[f], 0, 0, 0);
    }
  }
  const size_t pbase = (((size_t)bh * NC + c) * 64) * 64;
#pragma unroll
  for (int f = 0; f < 4; ++f) {
#pragma unroll
    for (int q = 0; q < 4; ++q) {
      const int i = wv * 16 + l4 * 4 + q;
      const int j = f * 16 + l15;
      Abuf[i * 68 + j] = (f16)((j < i) ? betas[i] * accS[f][q] : 0.f);
      pbuf[pbase + (size_t)i * 64 + j] = (f16)((j <= i) ? accP[f][q] : 0.f);
    }
  }
  __syncthreads();

#pragma unroll
  for (int i = 0; i < 4; ++i) {
    const int ch = tid + i * 256;
    const int rr = ch >> 4, kc = ch & 15;
    *(h8*)(QVs + ch * 8) = *(const h8*)(vb + gbase + (size_t)rr * rowstr + kc * 8);
  }

  {
    const int bi = wv;
    const int cc = l15;
    const f16* Ad = Abuf + (bi * 16) * 68 + bi * 16;
    float t[16];
    t[0] = (cc == 0) ? 1.f : 0.f;
#pragma unroll
    for (int i = 1; i < 16; ++i) {
      float s = (cc == i) ? 1.f : 0.f;
#pragma unroll
      for (int j = 0; j < i; ++j) s -= (float)Ad[i * 68 + j] * t[j];
      t[i] = s;
    }
    if (lane < 16) {
#pragma unroll
      for (int j4 = 0; j4 < 4; ++j4) {
        h4 v = {(f16)t[j4 * 4], (f16)t[j4 * 4 + 1], (f16)t[j4 * 4 + 2], (f16)t[j4 * 4 + 3]};
        *(h4*)(&Dt[bi][cc * 20 + j4 * 4]) = v;
      }
      const float bc = betas[bi * 16 + cc];
#pragma unroll
      for (int j = 0; j < 16; ++j) {
        Dr[bi][j * 20 + cc] = (f16)t[j];
        Tb[(bi * 16 + j) * 72 + bi * 16 + cc] = (f16)(t[j] * bc);
      }
    }
  }
  __syncthreads();

  const f16* AB10 = Abuf + 16 * 68 + 0;
  const f16* AB20 = Abuf + 32 * 68 + 0;
  const f16* AB21 = Abuf + 32 * 68 + 16;
  const f16* AB30 = Abuf + 48 * 68 + 0;
  const f16* AB31 = Abuf + 48 * 68 + 16;
  const f16* AB32 = Abuf + 48 * 68 + 32;
  f4 z = {};
  f4 x20, x30;

  if (wv == 0) wr_T(Xp[0], mm16(AB10, 68, Dt[0], z, l15, l4), l15, l4, 1.f);
  if (wv == 1) wr_T(Xp[1], mm16(AB21, 68, Dt[1], z, l15, l4), l15, l4, 1.f);
  if (wv == 2) wr_T(Xp[2], mm16(AB32, 68, Dt[2], z, l15, l4), l15, l4, 1.f);
  if (wv == 3) x20 = mm16(AB20, 68, Dt[0], z, l15, l4);
  __syncthreads();
  if (wv == 0) { f4 r = mm16(Dr[1], 20, Xp[0], z, l15, l4); wr_T(Tp[0], r, l15, l4, -1.f); wr_Tb(Tb, 1, 0, r, betas, l15, l4, -1.f); }
  if (wv == 1) { f4 r = mm16(Dr[2], 20, Xp[1], z, l15, l4); wr_T(Tp[1], r, l15, l4, -1.f); wr_Tb(Tb, 2, 1, r, betas, l15, l4, -1.f); }
  if (wv == 2) { f4 r = mm16(Dr[3], 20, Xp[2], z, l15, l4); wr_Tb(Tb, 3, 2, r, betas, l15, l4, -1.f); }
  if (wv == 3) x30 = mm16(AB30, 68, Dt[0], z, l15, l4);
  __syncthreads();
  if (wv == 3) wr_T(Xp[0], mm16(AB21, 68, Tp[0], x20, l15, l4), l15, l4, 1.f);
  if (wv == 1) { f4 r = mm16(AB31, 68, Dt[1], z, l15, l4); r = mm16(AB32, 68, Tp[1], r, l15, l4); wr_T(Xp[1], r, l15, l4, 1.f); }
  __syncthreads();
  if (wv == 3) { f4 r = mm16(Dr[2], 20, Xp[0], z, l15, l4); wr_T(Tp[2], r, l15, l4, -1.f); wr_Tb(Tb, 2, 0, r, betas, l15, l4, -1.f); }
  if (wv == 1) { f4 r = mm16(Dr[3], 20, Xp[1], z, l15, l4); wr_Tb(Tb, 3, 1, r, betas, l15, l4, -1.f); }
  __syncthreads();
  if (wv == 3) { f4 r = mm16(AB31, 68, Tp[0], x30, l15, l4); r = mm16(AB32, 68, Tp[2], r, l15, l4); wr_T(Xp[2], r, l15, l4, 1.f); }
  __syncthreads();
  if (wv == 3) { f4 r = mm16(Dr[3], 20, Xp[2], z, l15, l4); wr_Tb(Tb, 3, 0, r, betas, l15, l4, -1.f); }
  __syncthreads();

  const size_t wub = ((size_t)bh * NC + c) * 8192;
  const int koff = l4 * 8;
  f4 wacc[8] = {}, uacc[8] = {};
#pragma unroll
  for (int kc = 0; kc < 2; ++kc) {
    const h8 aT = *(const h8*)(Tb + (wv * 16 + l15) * 72 + kc * 32 + koff);
#pragma unroll
    for (int f = 0; f < 8; ++f) {
      const int d = f * 16 + l15, cD = d >> 3, d7 = d & 7;
      h8 bK, bV;
#pragma unroll
      for (int j = 0; j < 8; ++j) {
        const int t2 = kc * 32 + koff + j;
        const int pos = t2 * 128 + swz16(t2, cD) * 8 + d7;
        bK[j] = Ks[pos];
        bV[j] = QVs[pos];
      }
      wacc[f] = __builtin_amdgcn_mfma_f32_16x16x32_f16(aT, bK, wacc[f], 0, 0, 0);
      uacc[f] = __builtin_amdgcn_mfma_f32_16x16x32_f16(aT, bV, uacc[f], 0, 0, 0);
    }
  }
#pragma unroll
  for (int f = 0; f < 8; ++f) {
    const int d = f * 16 + l15, cD = d >> 3, d7 = d & 7;
#pragma unroll
    for (int q = 0; q < 4; ++q) {
      const int i = wv * 16 + l4 * 4 + q;
      wbuf[wub + (size_t)i * 128 + swz16(i, cD) * 8 + d7] = (f16)wacc[f][q];
    }
    h4 uv = {(f16)uacc[f][0], (f16)uacc[f][1], (f16)uacc[f][2], (f16)uacc[f][3]};
    *(h4*)(utbuf + wub + (size_t)d * 64 + wv * 16 + l4 * 4) = uv;
  }

#pragma unroll
  for (int i2 = 0; i2 < 4; ++i2) {
    const int ch = tid + i2 * 256;
    const int dp = ch & 127, c2 = ch >> 7;
    h8 v;
#pragma unroll
    for (int j = 0; j < 8; ++j) {
      const int i = c2 * 8 + j;
      v[j] = Ks[i * 128 + swz16(i, dp >> 3) * 8 + (dp & 7)];
    }
    *(h8*)(ktbuf + wub + (size_t)dp * 64 + (c2 ^ (dp & 7)) * 8) = v;
  }
}

// ---------------- Phase B: chunk recurrence (g in 0..7, 16 cols) -----------
__global__ __launch_bounds__(256) void phaseB(const f16* __restrict__ qb, const f16* __restrict__ ktbuf,
                                              const f16* __restrict__ wbuf, const f16* __restrict__ utbuf,
                                              const f16* __restrict__ pbuf, f16* __restrict__ obuf) {
  const int blk = blockIdx.x;
  const int bh = blk & 31, g = blk >> 5;
  const int b = bh >> 3, h = bh & 7;
  const int tid = threadIdx.x, lane = tid & 63, wv = tid >> 6;
  const int l15 = lane & 15, l4 = lane >> 4;

  __shared__ __align__(16) f16 Ws[2][8192];
  __shared__ __align__(16) f16 Qs[2][8192];
  __shared__ __align__(16) f16 Kts[2][8192];
  __shared__ __align__(16) f16 Rt[16 * 72];
  __shared__ __align__(16) f16 Ms[16 * 136];

  for (int i = tid; i < 16 * 136; i += 256) Ms[i] = (f16)0.f;
  f4 macc2[2] = {};

  const int arow = wv * 16 + l15;
  const int koff = l4 * 8;

  auto STAGE = [&](int c2, int buf) {
#pragma unroll
    for (int i = 0; i < 4; ++i) {
      const int ch = tid + i * 256;
      const size_t tb = ((size_t)bh * NC + c2) * 8192;
      __builtin_amdgcn_global_load_lds(AS1(wbuf + tb + ch * 8), AS3(Ws[buf] + ch * 8), 16, 0, 0);
      __builtin_amdgcn_global_load_lds(AS1(ktbuf + tb + ch * 8), AS3(Kts[buf] + ch * 8), 16, 0, 0);
      const int rr = ch >> 4, kc2 = ch & 15;
      __builtin_amdgcn_global_load_lds(AS1(qb + ((size_t)((c2 * 64 + rr) * 4 + b)) * 1024 + h * 128 + kc2 * 8),
                                       AS3(Qs[buf] + ch * 8), 16, 0, 0);
    }
  };

  STAGE(0, 0);
  asm volatile("s_waitcnt vmcnt(0)" ::: "memory");
  __builtin_amdgcn_s_barrier();

  for (int c = 0; c < NC; ++c) {
    const int cur = c & 1, nxt = cur ^ 1;
    const size_t pcb = ((size_t)bh * NC + c) * 4096;
    const h8 aP0 = *(const h8*)(pbuf + pcb + arow * 64 + koff);
    const h8 aP1 = *(const h8*)(pbuf + pcb + arow * 64 + 32 + koff);
    const size_t ucb = ((size_t)bh * NC + c) * 8192;
    const h4 u0 = *(const h4*)(utbuf + ucb + (size_t)(g * 16 + l15) * 64 + wv * 16 + l4 * 4);
    asm volatile("s_waitcnt vmcnt(3)" ::: "memory");
    asm volatile("s_waitcnt lgkmcnt(0)" ::: "memory");
    __builtin_amdgcn_s_barrier();
    if (c + 1 < NC) STAGE(c + 1, nxt);

    f4 accR = {}, accO = {};
    __builtin_amdgcn_s_setprio(1);
#pragma unroll
    for (int kc = 0; kc < 4; ++kc) {
      const int c4 = kc * 4 + l4;
      const h8 aW = *(const h8*)(Ws[cur] + arow * 128 + swz16(arow, c4) * 8);
      const h8 aQ = *(const h8*)(Qs[cur] + arow * 128 + swz16(arow, c4) * 8);
      const h8 bM = *(const h8*)(Ms + l15 * 136 + kc * 32 + koff);
      accR = __builtin_amdgcn_mfma_f32_16x16x32_f16(aW, bM, accR, 0, 0, 0);
      accO = __builtin_amdgcn_mfma_f32_16x16x32_f16(aQ, bM, accO, 0, 0, 0);
    }
    __builtin_amdgcn_s_setprio(0);
    if (c + 1 < NC) asm volatile("s_waitcnt vmcnt(12)" ::: "memory");
    else            asm volatile("s_waitcnt vmcnt(0)" ::: "memory");
    {
      h4 rw;
#pragma unroll
      for (int q = 0; q < 4; ++q) {
        const float rv = (float)u0[q] - accR[q];
        rw[q] = (f16)rv;
      }
      *(h4*)(Rt + l15 * 72 + wv * 16 + l4 * 4) = rw;
    }
    asm volatile("s_waitcnt lgkmcnt(0)" ::: "memory");
    __builtin_amdgcn_s_barrier();

#pragma unroll
    for (int kc = 0; kc < 2; ++kc) {
      const h8 aP = kc ? aP1 : aP0;
      const h8 bR = *(const h8*)(Rt + l15 * 72 + kc * 32 + koff);
      accO = __builtin_amdgcn_mfma_f32_16x16x32_f16(aP, bR, accO, 0, 0, 0);
    }
#pragma unroll
    for (int q = 0; q < 4; ++q) {
      const int i = wv * 16 + l4 * 4 + q;
      obuf[((size_t)(c * 64 + i) * Bb_ + b) * Dd + h * 128 + g * 16 + l15] = (f16)accO[q];
    }

#pragma unroll
    for (int kc = 0; kc < 2; ++kc) {
      const h8 aR0 = *(const h8*)(Rt + l15 * 72 + kc * 32 + koff);
#pragma unroll
      for (int cf = 0; cf < 2; ++cf) {
        const int kcol = wv * 32 + cf * 16 + l15;
        const int c2 = kc * 4 + l4;
        const h8 bKv = *(const h8*)(Kts[cur] + kcol * 64 + (c2 ^ (kcol & 7)) * 8);
        macc2[cf] = __builtin_amdgcn_mfma_f32_16x16x32_f16(aR0, bKv, macc2[cf], 0, 0, 0);
      }
    }
#pragma unroll
    for (int cf = 0; cf < 2; ++cf)
#pragma unroll
      for (int q = 0; q < 4; ++q) {
        const int cr = l4 * 4 + q;
        const int kcol = wv * 32 + cf * 16 + l15;
        Ms[cr * 136 + kcol] = (f16)macc2[cf][q];
      }
  }
}

// ---------------------------------------------------------------------------
extern "C" void kernel_launch(void* const* d_in, const int* in_sizes, int n_in,
                              void* d_out, int out_size, void* d_ws, size_t ws_size,
                              hipStream_t stream) {
  (void)in_sizes; (void)n_in;
  const float* input = (const float*)d_in[0];
  const float* Wq = (const float*)d_in[1];
  const float* Wk = (const float*)d_in[2];
  const float* Wv = (const float*)d_in[3];
  const float* Wb = (const float*)d_in[4];
  const float* Wo = (const float*)d_in[5];
  const float* onw = (const float*)d_in[6];
  const float* n1w = (const float*)d_in[7];
  const float* n2w = (const float*)d_in[8];
  const float* Wg = (const float*)d_in[9];
  const float* Wd = (const float*)d_in[10];
  const float* fnw = (const float*)d_in[11];

  char* ws = (char*)d_ws;
  size_t off = 0;
  auto alloc = [&](size_t bytes) { void* p = ws + off; off += (bytes + 255) & ~(size_t)255; return p; };
  const size_t RD = 8192ull * 1024ull;
  f16*  x     = (f16*)alloc(RD * 2);
  f16*  qb    = (f16*)alloc(RD * 2);
  f16*  kbuf  = (f16*)alloc(RD * 2);
  f16*  vbuf  = (f16*)alloc(RD * 2);
  float* beta = (float*)alloc(8192ull * 8 * 4);
  float* rs   = (float*)alloc(8192ull * 4);
  float* Wb2  = (float*)alloc(2ull * 1024 * 8 * 4);
  f16*  wbuf  = (f16*)alloc(RD * 2);
  f16*  utbuf = (f16*)alloc(RD * 2);
  f16*  ktbuf = (f16*)alloc(RD * 2);
  f16*  pbuf  = (f16*)alloc(32ull * 32 * 64 * 64 * 2);
  char* arena = (char*)alloc(3 * RD * 2);
  f16*  WqkvT = (f16*)alloc(2ull * 3072 * 1024 * 2);
  f16*  WoT   = (f16*)alloc(2ull * 1024 * 1024 * 2);
  f16*  WgT   = (f16*)alloc(2ull * 5632 * 1024 * 2);
  f16*  WdT   = (f16*)alloc(2ull * 1024 * 2816 * 2);
  if (off > ws_size) {
    fill_k<<<(out_size + 255) / 256, 256, 0, stream>>>((float*)d_out, out_size, 1.0e6f);
    return;
  }
  f16* obuf = (f16*)arena;
  f16* my = qb;
  f16* ob = wbuf;

  cvt_k<<<4096, 256, 0, stream>>>(input, x);
  // ---- weight prep, both layers in one shot ----
  transpose_k<1><<<dim3(32, 32, 2), 256, 0, stream>>>(Wq, n1w, WqkvT, 1024, 1024, 1024ull * 1024, 3072ull * 1024);
  transpose_k<1><<<dim3(32, 32, 2), 256, 0, stream>>>(Wk, n1w, WqkvT + 1024ull * 1024, 1024, 1024, 1024ull * 1024, 3072ull * 1024);
  transpose_k<1><<<dim3(32, 32, 2), 256, 0, stream>>>(Wv, n1w, WqkvT + 2048ull * 1024, 1024, 1024, 1024ull * 1024, 3072ull * 1024);
  transpose_k<0><<<dim3(32, 32, 2), 256, 0, stream>>>(Wo, nullptr, WoT, 1024, 1024, 1024ull * 1024, 1024ull * 1024);
  transpose_k<1><<<dim3(176, 32, 2), 256, 0, stream>>>(Wg, n2w, WgT, 1024, 5632, 1024ull * 5632, 5632ull * 1024);
  transpose_k<0><<<dim3(32, 88, 2), 256, 0, stream>>>(Wd, nullptr, WdT, 2816, 1024, 2816ull * 1024, 1024ull * 2816);
  bweight_k<<<64, 256, 0, stream>>>(Wb, n1w, Wb2);

  for (int l = 0; l < 2; ++l) {
    const f16* WqkvTl = WqkvT + (size_t)l * 3072 * 1024;
    const f16* WoTl   = WoT + (size_t)l * 1024 * 1024;
    const f16* WgTl   = WgT + (size_t)l * 5632 * 1024;
    const f16* WdTl   = WdT + (size_t)l * 1024 * 2816;

    rsbeta_k<<<2048, 256, 0, stream>>>(x, Wb2 + (size_t)l * 8192, rs, beta);
    gemmQKV<<<32 * 24, 512, 0, stream>>>(x, WqkvTl, rs, qb, kbuf, vbuf, 1024, 24);
    phaseA<<<1024, 256, 0, stream>>>(kbuf, qb, vbuf, beta, wbuf, utbuf, pbuf, ktbuf);
    phaseB<<<256, 256, 0, stream>>>(qb, ktbuf, wbuf, utbuf, pbuf, obuf);
    onorm_k<<<8192, 256, 0, stream>>>(obuf, onw + l * 128, ob);
    gemm2<1, 0><<<32 * 8, 512, 0, stream>>>(ob, WoTl, x, nullptr, 8192, 1024, 1024, 8);

    rowscale_k<<<2048, 256, 0, stream>>>(x, rs);
    gemmGLU<<<32 * 22, 512, 0, stream>>>(x, WgTl, rs, my, 1024, 22);
    gemm2<1, 0><<<32 * 8, 512, 0, stream>>>(my, WdTl, x, nullptr, 8192, 1024, 2816, 8);
  }
  rmsnorm_f<<<8192, 256, 0, stream>>>(x, fnw, (float*)d_out);
}

// Round 14
// 921.293 us; speedup vs baseline: 1.0535x; 1.0025x over previous
//
#include <hip/hip_runtime.h>
#include <hip/hip_bf16.h>
#include <cstdint>

// DeltaNet forward, MI355X. Round 14: epilogue fusions — Wo-GEMM accumulates
// row sumsq for norm2 (rowscale_k killed); cvt+rsbeta fused for layer 0.

typedef _Float16 f16;
typedef __attribute__((ext_vector_type(8))) _Float16 h8;
typedef __attribute__((ext_vector_type(4))) _Float16 h4;
typedef __attribute__((ext_vector_type(4))) float f4;

#define DEV __device__ __forceinline__

static constexpr int Bb_ = 4;
static constexpr int Hh  = 8;
static constexpr int Dd  = 1024;
static constexpr int Tt  = 2048;
static constexpr int NC  = 32;

DEV float siluf(float x) { return x / (1.f + expf(-x)); }
DEV int swz16(int row, int c) { return (c & 8) | ((c & 7) ^ (row & 7)); }

#define AS1(p) ((const __attribute__((address_space(1))) void*)(uintptr_t)(p))
#define AS3(p) ((__attribute__((address_space(3))) void*)(uint32_t)(uintptr_t)(p))

DEV h8 rd_sw(const f16* T, int row, int chunk) {
  return *(const h8*)(T + (((row << 3) | (chunk ^ (row & 7))) * 8));
}

// ===== 2-phase GEMM: C[M,N] op= A[M,K]*Bt[N,K]^T, BN=128 ====================
// EPI 1: f16 += ; 2: f16 store. SC: row-scale from rs. RSQ: accumulate row
// sum-of-squares of the written values into rs (atomicAdd), for next norm.
template<int EPI, int SC, int RSQ>
__global__ __launch_bounds__(512, 2) void gemm2(const f16* __restrict__ A, const f16* __restrict__ Bt,
                                                void* __restrict__ C, float* __restrict__ rs,
                                                int M, int N, int K, int gx) {
  __shared__ __align__(16) f16 ldsA[2][16384];
  __shared__ __align__(16) f16 ldsB[2][8192];
  __shared__ float ps[4][256];
  const int tid = threadIdx.x, lane = tid & 63, w = tid >> 6;
  const int l15 = lane & 15, l4 = lane >> 4;
  const int wr = w >> 2, wc = w & 3;
  const int nwg = gridDim.x;
  int flat = blockIdx.x;
  if ((nwg & 7) == 0) flat = (flat & 7) * (nwg >> 3) + (flat >> 3);
  const int bx = flat % gx, by = flat / gx;

  const f16* Ab = A + (size_t)by * 256 * K;
  const f16* Bb = Bt + (size_t)bx * 128 * K;
  const int NT = K >> 6;
  f4 acc[8][2] = {};

  const int r0 = tid >> 3;
  const size_t soff0 = (size_t)r0 * K + (size_t)(((tid & 7) ^ (r0 & 7)) * 8);
  const size_t soff1 = soff0 + (size_t)64 * K;
  const int dof = tid * 8;
  auto STG = [&](const f16* base, f16* dst) {
    __builtin_amdgcn_global_load_lds(AS1(base + soff0), AS3(dst + dof), 16, 0, 0);
    __builtin_amdgcn_global_load_lds(AS1(base + soff1), AS3(dst + 4096 + dof), 16, 0, 0);
  };

  STG(Bb, ldsB[0]);
  STG(Ab, ldsA[0]);
  STG(Ab + (size_t)128 * K, ldsA[0] + 8192);
  if (NT > 1) {
    STG(Bb + 64, ldsB[1]);
    asm volatile("s_waitcnt vmcnt(2)");
  } else {
    asm volatile("s_waitcnt vmcnt(0)");
  }
  __builtin_amdgcn_s_barrier();

  for (int t = 0; t < NT; ++t) {
    const int cur = t & 1, nxt = cur ^ 1;
    const f16* cA = ldsA[cur];
    const f16* cB = ldsB[cur];
    h8 b[2][2], aX[2][2], aY[2][2];
#pragma unroll
    for (int cf = 0; cf < 2; ++cf)
#pragma unroll
      for (int ks = 0; ks < 2; ++ks)
        b[cf][ks] = rd_sw(cB, wc * 32 + cf * 16 + l15, ks * 4 + l4);
#pragma unroll
    for (int fr = 0; fr < 2; ++fr)
#pragma unroll
      for (int ks = 0; ks < 2; ++ks)
        aX[fr][ks] = rd_sw(cA, wr * 128 + fr * 16 + l15, ks * 4 + l4);
    if (t + 1 < NT) { STG(Ab + (t + 1) * 64, ldsA[nxt]); STG(Ab + (size_t)128 * K + (t + 1) * 64, ldsA[nxt] + 8192); }
    __builtin_amdgcn_s_setprio(1);
#pragma unroll
    for (int fr = 0; fr < 2; ++fr)
#pragma unroll
      for (int cf = 0; cf < 2; ++cf)
#pragma unroll
        for (int ks = 0; ks < 2; ++ks)
          acc[fr][cf] = __builtin_amdgcn_mfma_f32_16x16x32_f16(aX[fr][ks], b[cf][ks], acc[fr][cf], 0, 0, 0);
#pragma unroll
    for (int fr = 0; fr < 2; ++fr)
#pragma unroll
      for (int ks = 0; ks < 2; ++ks)
        aY[fr][ks] = rd_sw(cA, wr * 128 + 32 + fr * 16 + l15, ks * 4 + l4);
#pragma unroll
    for (int fr = 0; fr < 2; ++fr)
#pragma unroll
      for (int cf = 0; cf < 2; ++cf)
#pragma unroll
        for (int ks = 0; ks < 2; ++ks)
          acc[2 + fr][cf] = __builtin_amdgcn_mfma_f32_16x16x32_f16(aY[fr][ks], b[cf][ks], acc[2 + fr][cf], 0, 0, 0);
    __builtin_amdgcn_s_setprio(0);
    __builtin_amdgcn_s_barrier();
#pragma unroll
    for (int fr = 0; fr < 2; ++fr)
#pragma unroll
      for (int ks = 0; ks < 2; ++ks)
        aX[fr][ks] = rd_sw(cA, wr * 128 + 64 + fr * 16 + l15, ks * 4 + l4);
    if (t + 2 < NT) STG(Bb + (t + 2) * 64, ldsB[cur]);
    __builtin_amdgcn_s_setprio(1);
#pragma unroll
    for (int fr = 0; fr < 2; ++fr)
#pragma unroll
      for (int cf = 0; cf < 2; ++cf)
#pragma unroll
        for (int ks = 0; ks < 2; ++ks)
          acc[4 + fr][cf] = __builtin_amdgcn_mfma_f32_16x16x32_f16(aX[fr][ks], b[cf][ks], acc[4 + fr][cf], 0, 0, 0);
#pragma unroll
    for (int fr = 0; fr < 2; ++fr)
#pragma unroll
      for (int ks = 0; ks < 2; ++ks)
        aY[fr][ks] = rd_sw(cA, wr * 128 + 96 + fr * 16 + l15, ks * 4 + l4);
#pragma unroll
    for (int fr = 0; fr < 2; ++fr)
#pragma unroll
      for (int cf = 0; cf < 2; ++cf)
#pragma unroll
        for (int ks = 0; ks < 2; ++ks)
          acc[6 + fr][cf] = __builtin_amdgcn_mfma_f32_16x16x32_f16(aY[fr][ks], b[cf][ks], acc[6 + fr][cf], 0, 0, 0);
    __builtin_amdgcn_s_setprio(0);
    if (t + 2 < NT)      asm volatile("s_waitcnt vmcnt(2)" ::: "memory");
    else if (t + 1 < NT) asm volatile("s_waitcnt vmcnt(0)" ::: "memory");
    __builtin_amdgcn_s_barrier();
  }

#pragma unroll
  for (int fr = 0; fr < 8; ++fr) {
#pragma unroll
    for (int q = 0; q < 4; ++q) {
      const int row0 = by * 256 + wr * 128 + fr * 16 + l4 * 4 + q;
      float s2 = 0.f;
#pragma unroll
      for (int cf = 0; cf < 2; ++cf) {
        const int col = bx * 128 + wc * 32 + cf * 16 + l15;
        const size_t idx = (size_t)row0 * N + col;
        float v = acc[fr][cf][q];
        if (SC) v *= rs[row0];
        if (EPI == 1) {
          const float xn = (float)((f16*)C)[idx] + v;
          ((f16*)C)[idx] = (f16)xn;
          if (RSQ) s2 += xn * xn;
        }
        if (EPI == 2) ((f16*)C)[idx] = (f16)v;
      }
      if (RSQ) {
#pragma unroll
        for (int m = 1; m < 16; m <<= 1) s2 += __shfl_xor(s2, m);
        if (l15 == 0) ps[wc][wr * 128 + fr * 16 + l4 * 4 + q] = s2;
      }
    }
  }
  if (RSQ) {
    __syncthreads();
    if (tid < 256) atomicAdd(&rs[by * 256 + tid], ps[0][tid] + ps[1][tid] + ps[2][tid] + ps[3][tid]);
  }
}

// ============ QKV GEMM with fused silu+l2norm epilogue =====================
__global__ __launch_bounds__(512, 2) void gemmQKV(const f16* __restrict__ A, const f16* __restrict__ Bt,
                                                  const float* __restrict__ rs, f16* __restrict__ qb,
                                                  f16* __restrict__ kb, f16* __restrict__ vb,
                                                  int K, int gx) {
  __shared__ __align__(16) f16 ldsA[2][16384];
  __shared__ __align__(16) f16 ldsB[2][8192];
  __shared__ float ps[4][256];
  const int tid = threadIdx.x, lane = tid & 63, w = tid >> 6;
  const int l15 = lane & 15, l4 = lane >> 4;
  const int wr = w >> 2, wc = w & 3;
  const int nwg = gridDim.x;
  int flat = blockIdx.x;
  if ((nwg & 7) == 0) flat = (flat & 7) * (nwg >> 3) + (flat >> 3);
  const int bx = flat % gx, by = flat / gx;

  const f16* Ab = A + (size_t)by * 256 * K;
  const f16* Bb = Bt + (size_t)bx * 128 * K;
  const int NT = K >> 6;
  f4 acc[8][2] = {};

  const int r0 = tid >> 3;
  const size_t soff0 = (size_t)r0 * K + (size_t)(((tid & 7) ^ (r0 & 7)) * 8);
  const size_t soff1 = soff0 + (size_t)64 * K;
  const int dof = tid * 8;
  auto STG = [&](const f16* base, f16* dst) {
    __builtin_amdgcn_global_load_lds(AS1(base + soff0), AS3(dst + dof), 16, 0, 0);
    __builtin_amdgcn_global_load_lds(AS1(base + soff1), AS3(dst + 4096 + dof), 16, 0, 0);
  };

  STG(Bb, ldsB[0]);
  STG(Ab, ldsA[0]);
  STG(Ab + (size_t)128 * K, ldsA[0] + 8192);
  if (NT > 1) {
    STG(Bb + 64, ldsB[1]);
    asm volatile("s_waitcnt vmcnt(2)");
  } else {
    asm volatile("s_waitcnt vmcnt(0)");
  }
  __builtin_amdgcn_s_barrier();

  for (int t = 0; t < NT; ++t) {
    const int cur = t & 1, nxt = cur ^ 1;
    const f16* cA = ldsA[cur];
    const f16* cB = ldsB[cur];
    h8 b[2][2], aX[2][2], aY[2][2];
#pragma unroll
    for (int cf = 0; cf < 2; ++cf)
#pragma unroll
      for (int ks = 0; ks < 2; ++ks)
        b[cf][ks] = rd_sw(cB, wc * 32 + cf * 16 + l15, ks * 4 + l4);
#pragma unroll
    for (int fr = 0; fr < 2; ++fr)
#pragma unroll
      for (int ks = 0; ks < 2; ++ks)
        aX[fr][ks] = rd_sw(cA, wr * 128 + fr * 16 + l15, ks * 4 + l4);
    if (t + 1 < NT) { STG(Ab + (t + 1) * 64, ldsA[nxt]); STG(Ab + (size_t)128 * K + (t + 1) * 64, ldsA[nxt] + 8192); }
    __builtin_amdgcn_s_setprio(1);
#pragma unroll
    for (int fr = 0; fr < 2; ++fr)
#pragma unroll
      for (int cf = 0; cf < 2; ++cf)
#pragma unroll
        for (int ks = 0; ks < 2; ++ks)
          acc[fr][cf] = __builtin_amdgcn_mfma_f32_16x16x32_f16(aX[fr][ks], b[cf][ks], acc[fr][cf], 0, 0, 0);
#pragma unroll
    for (int fr = 0; fr < 2; ++fr)
#pragma unroll
      for (int ks = 0; ks < 2; ++ks)
        aY[fr][ks] = rd_sw(cA, wr * 128 + 32 + fr * 16 + l15, ks * 4 + l4);
#pragma unroll
    for (int fr = 0; fr < 2; ++fr)
#pragma unroll
      for (int cf = 0; cf < 2; ++cf)
#pragma unroll
        for (int ks = 0; ks < 2; ++ks)
          acc[2 + fr][cf] = __builtin_amdgcn_mfma_f32_16x16x32_f16(aY[fr][ks], b[cf][ks], acc[2 + fr][cf], 0, 0, 0);
    __builtin_amdgcn_s_setprio(0);
    __builtin_amdgcn_s_barrier();
#pragma unroll
    for (int fr = 0; fr < 2; ++fr)
#pragma unroll
      for (int ks = 0; ks < 2; ++ks)
        aX[fr][ks] = rd_sw(cA, wr * 128 + 64 + fr * 16 + l15, ks * 4 + l4);
    if (t + 2 < NT) STG(Bb + (t + 2) * 64, ldsB[cur]);
    __builtin_amdgcn_s_setprio(1);
#pragma unroll
    for (int fr = 0; fr < 2; ++fr)
#pragma unroll
      for (int cf = 0; cf < 2; ++cf)
#pragma unroll
        for (int ks = 0; ks < 2; ++ks)
          acc[4 + fr][cf] = __builtin_amdgcn_mfma_f32_16x16x32_f16(aX[fr][ks], b[cf][ks], acc[4 + fr][cf], 0, 0, 0);
#pragma unroll
    for (int fr = 0; fr < 2; ++fr)
#pragma unroll
      for (int ks = 0; ks < 2; ++ks)
        aY[fr][ks] = rd_sw(cA, wr * 128 + 96 + fr * 16 + l15, ks * 4 + l4);
#pragma unroll
    for (int fr = 0; fr < 2; ++fr)
#pragma unroll
      for (int cf = 0; cf < 2; ++cf)
#pragma unroll
        for (int ks = 0; ks < 2; ++ks)
          acc[6 + fr][cf] = __builtin_amdgcn_mfma_f32_16x16x32_f16(aY[fr][ks], b[cf][ks], acc[6 + fr][cf], 0, 0, 0);
    __builtin_amdgcn_s_setprio(0);
    if (t + 2 < NT)      asm volatile("s_waitcnt vmcnt(2)" ::: "memory");
    else if (t + 1 < NT) asm volatile("s_waitcnt vmcnt(0)" ::: "memory");
    __builtin_amdgcn_s_barrier();
  }

#pragma unroll
  for (int fr = 0; fr < 8; ++fr)
#pragma unroll
    for (int q = 0; q < 4; ++q) {
      const int grow = by * 256 + wr * 128 + fr * 16 + l4 * 4 + q;
      const float s = rs[grow];
#pragma unroll
      for (int cf = 0; cf < 2; ++cf)
        acc[fr][cf][q] = siluf(s * acc[fr][cf][q]);
    }
  if (bx < 16) {
    float sq[8][4];
#pragma unroll
    for (int fr = 0; fr < 8; ++fr)
#pragma unroll
      for (int q = 0; q < 4; ++q) {
        float v = acc[fr][0][q] * acc[fr][0][q] + acc[fr][1][q] * acc[fr][1][q];
#pragma unroll
        for (int m = 1; m < 16; m <<= 1) v += __shfl_xor(v, m);
        sq[fr][q] = v;
      }
    if (l15 == 0) {
#pragma unroll
      for (int fr = 0; fr < 8; ++fr)
#pragma unroll
        for (int q = 0; q < 4; ++q)
          ps[wc][wr * 128 + fr * 16 + l4 * 4 + q] = sq[fr][q];
    }
    __syncthreads();
#pragma unroll
    for (int fr = 0; fr < 8; ++fr)
#pragma unroll
      for (int q = 0; q < 4; ++q) {
        const int rl = wr * 128 + fr * 16 + l4 * 4 + q;
        const float sc = rsqrtf(ps[0][rl] + ps[1][rl] + ps[2][rl] + ps[3][rl] + 1e-6f);
#pragma unroll
        for (int cf = 0; cf < 2; ++cf) acc[fr][cf][q] *= sc;
      }
  }
  f16* dst = (bx < 8) ? qb : ((bx < 16) ? kb : vb);
  const int head = bx & 7;
#pragma unroll
  for (int fr = 0; fr < 8; ++fr)
#pragma unroll
    for (int cf = 0; cf < 2; ++cf)
#pragma unroll
      for (int q = 0; q < 4; ++q) {
        const int grow = by * 256 + wr * 128 + fr * 16 + l4 * 4 + q;
        const int i = (grow >> 2) & 63;
        const int dh = wc * 32 + cf * 16 + l15;
        dst[(size_t)grow * 1024 + head * 128 + swz16(i, dh >> 3) * 8 + (dh & 7)] = (f16)acc[fr][cf][q];
      }
}

// ============ fused GLU GEMM (reads rsq, computes scale inline) ============
__global__ __launch_bounds__(512, 2) void gemmGLU(const f16* __restrict__ A, const f16* __restrict__ WgT,
                                                  const float* __restrict__ rsq, f16* __restrict__ my,
                                                  int K, int gx) {
  __shared__ __align__(16) f16 ldsA[2][16384];
  __shared__ __align__(16) f16 ldsG[2][8192];
  __shared__ __align__(16) f16 ldsY[2][8192];
  const int tid = threadIdx.x, lane = tid & 63, w = tid >> 6;
  const int l15 = lane & 15, l4 = lane >> 4;
  const int wr = w >> 2, wc = w & 3;
  const int nwg = gridDim.x;
  int flat = blockIdx.x;
  if ((nwg & 7) == 0) flat = (flat & 7) * (nwg >> 3) + (flat >> 3);
  const int bx = flat % gx, by = flat / gx;

  const f16* Ab = A + (size_t)by * 256 * K;
  const f16* Gb = WgT + (size_t)bx * 128 * K;
  const f16* Yb = WgT + (size_t)(2816 + bx * 128) * K;
  const int NT = K >> 6;
  f4 accG[8][2] = {}, accY[8][2] = {};

  const int r0 = tid >> 3;
  const size_t soff0 = (size_t)r0 * K + (size_t)(((tid & 7) ^ (r0 & 7)) * 8);
  const size_t soff1 = soff0 + (size_t)64 * K;
  const int dof = tid * 8;
  auto STG = [&](const f16* base, f16* dst) {
    __builtin_amdgcn_global_load_lds(AS1(base + soff0), AS3(dst + dof), 16, 0, 0);
    __builtin_amdgcn_global_load_lds(AS1(base + soff1), AS3(dst + 4096 + dof), 16, 0, 0);
  };

  STG(Gb, ldsG[0]);
  STG(Yb, ldsY[0]);
  STG(Ab, ldsA[0]);
  STG(Ab + (size_t)128 * K, ldsA[0] + 8192);
  if (NT > 1) {
    STG(Gb + 64, ldsG[1]);
    STG(Yb + 64, ldsY[1]);
    asm volatile("s_waitcnt vmcnt(4)");
  } else {
    asm volatile("s_waitcnt vmcnt(0)");
  }
  __builtin_amdgcn_s_barrier();

  for (int t = 0; t < NT; ++t) {
    const int cur = t & 1, nxt = cur ^ 1;
    const f16* cA = ldsA[cur];
    h8 bg[2][2], byv[2][2], aX[2][2], aY[2][2];
#pragma unroll
    for (int cf = 0; cf < 2; ++cf)
#pragma unroll
      for (int ks = 0; ks < 2; ++ks) {
        bg[cf][ks] = rd_sw(ldsG[cur], wc * 32 + cf * 16 + l15, ks * 4 + l4);
        byv[cf][ks] = rd_sw(ldsY[cur], wc * 32 + cf * 16 + l15, ks * 4 + l4);
      }
#pragma unroll
    for (int fr = 0; fr < 2; ++fr)
#pragma unroll
      for (int ks = 0; ks < 2; ++ks)
        aX[fr][ks] = rd_sw(cA, wr * 128 + fr * 16 + l15, ks * 4 + l4);
    if (t + 1 < NT) { STG(Ab + (t + 1) * 64, ldsA[nxt]); STG(Ab + (size_t)128 * K + (t + 1) * 64, ldsA[nxt] + 8192); }
    __builtin_amdgcn_s_setprio(1);
#pragma unroll
    for (int fr = 0; fr < 2; ++fr)
#pragma unroll
      for (int cf = 0; cf < 2; ++cf)
#pragma unroll
        for (int ks = 0; ks < 2; ++ks) {
          accG[fr][cf] = __builtin_amdgcn_mfma_f32_16x16x32_f16(aX[fr][ks], bg[cf][ks], accG[fr][cf], 0, 0, 0);
          accY[fr][cf] = __builtin_amdgcn_mfma_f32_16x16x32_f16(aX[fr][ks], byv[cf][ks], accY[fr][cf], 0, 0, 0);
        }
#pragma unroll
    for (int fr = 0; fr < 2; ++fr)
#pragma unroll
      for (int ks = 0; ks < 2; ++ks)
        aY[fr][ks] = rd_sw(cA, wr * 128 + 32 + fr * 16 + l15, ks * 4 + l4);
#pragma unroll
    for (int fr = 0; fr < 2; ++fr)
#pragma unroll
      for (int cf = 0; cf < 2; ++cf)
#pragma unroll
        for (int ks = 0; ks < 2; ++ks) {
          accG[2 + fr][cf] = __builtin_amdgcn_mfma_f32_16x16x32_f16(aY[fr][ks], bg[cf][ks], accG[2 + fr][cf], 0, 0, 0);
          accY[2 + fr][cf] = __builtin_amdgcn_mfma_f32_16x16x32_f16(aY[fr][ks], byv[cf][ks], accY[2 + fr][cf], 0, 0, 0);
        }
    __builtin_amdgcn_s_setprio(0);
    __builtin_amdgcn_s_barrier();
#pragma unroll
    for (int fr = 0; fr < 2; ++fr)
#pragma unroll
      for (int ks = 0; ks < 2; ++ks)
        aX[fr][ks] = rd_sw(cA, wr * 128 + 64 + fr * 16 + l15, ks * 4 + l4);
    if (t + 2 < NT) { STG(Gb + (t + 2) * 64, ldsG[cur]); STG(Yb + (t + 2) * 64, ldsY[cur]); }
    __builtin_amdgcn_s_setprio(1);
#pragma unroll
    for (int fr = 0; fr < 2; ++fr)
#pragma unroll
      for (int cf = 0; cf < 2; ++cf)
#pragma unroll
        for (int ks = 0; ks < 2; ++ks) {
          accG[4 + fr][cf] = __builtin_amdgcn_mfma_f32_16x16x32_f16(aX[fr][ks], bg[cf][ks], accG[4 + fr][cf], 0, 0, 0);
          accY[4 + fr][cf] = __builtin_amdgcn_mfma_f32_16x16x32_f16(aX[fr][ks], byv[cf][ks], accY[4 + fr][cf], 0, 0, 0);
        }
#pragma unroll
    for (int fr = 0; fr < 2; ++fr)
#pragma unroll
      for (int ks = 0; ks < 2; ++ks)
        aY[fr][ks] = rd_sw(cA, wr * 128 + 96 + fr * 16 + l15, ks * 4 + l4);
#pragma unroll
    for (int fr = 0; fr < 2; ++fr)
#pragma unroll
      for (int cf = 0; cf < 2; ++cf)
#pragma unroll
        for (int ks = 0; ks < 2; ++ks) {
          accG[6 + fr][cf] = __builtin_amdgcn_mfma_f32_16x16x32_f16(aY[fr][ks], bg[cf][ks], accG[6 + fr][cf], 0, 0, 0);
          accY[6 + fr][cf] = __builtin_amdgcn_mfma_f32_16x16x32_f16(aY[fr][ks], byv[cf][ks], accY[6 + fr][cf], 0, 0, 0);
        }
    __builtin_amdgcn_s_setprio(0);
    if (t + 2 < NT)      asm volatile("s_waitcnt vmcnt(4)" ::: "memory");
    else if (t + 1 < NT) asm volatile("s_waitcnt vmcnt(0)" ::: "memory");
    __builtin_amdgcn_s_barrier();
  }

#pragma unroll
  for (int fr = 0; fr < 8; ++fr) {
#pragma unroll
    for (int cf = 0; cf < 2; ++cf) {
      const int row0 = by * 256 + wr * 128 + fr * 16 + l4 * 4;
      const int col = bx * 128 + wc * 32 + cf * 16 + l15;
#pragma unroll
      for (int q = 0; q < 4; ++q) {
        const float s = rsqrtf(rsq[row0 + q] * (1.f / 1024.f) + 1e-6f);
        my[(size_t)(row0 + q) * 2816 + col] = (f16)(siluf(s * accG[fr][cf][q]) * (s * accY[fr][cf][q]));
      }
    }
  }
}

// -------- fused cvt(f32->f16) + rowscale + beta (layer 0) ------------------
__global__ __launch_bounds__(256) void cvt_row(const float* __restrict__ in, f16* __restrict__ x,
                                               const float* __restrict__ Wb2, float* __restrict__ rs,
                                               float* __restrict__ beta) {
  const int tid = threadIdx.x, lane = tid & 63, wv = tid >> 6;
  const int r = blockIdx.x * 4 + wv;
  const float* row = in + (size_t)r * 1024 + lane * 16;
  float val[16];
#pragma unroll
  for (int j = 0; j < 4; ++j) {
    const float4 v = *(const float4*)(row + j * 4);
    val[j * 4] = v.x; val[j * 4 + 1] = v.y; val[j * 4 + 2] = v.z; val[j * 4 + 3] = v.w;
  }
  h8 o0, o1;
#pragma unroll
  for (int j = 0; j < 8; ++j) { o0[j] = (f16)val[j]; o1[j] = (f16)val[j + 8]; }
  *(h8*)(x + (size_t)r * 1024 + lane * 16) = o0;
  *(h8*)(x + (size_t)r * 1024 + lane * 16 + 8) = o1;

  const float* wb = Wb2 + (size_t)(lane * 16) * 8;
  float ss = 0.f;
  float acc[8] = {};
#pragma unroll
  for (int e = 0; e < 8; ++e) {
    const float x0 = val[e], x1 = val[e + 8];
    ss += x0 * x0 + x1 * x1;
    const float4 w0a = *(const float4*)(wb + e * 8);
    const float4 w0b = *(const float4*)(wb + e * 8 + 4);
    const float4 w1a = *(const float4*)(wb + (e + 8) * 8);
    const float4 w1b = *(const float4*)(wb + (e + 8) * 8 + 4);
    acc[0] += x0 * w0a.x + x1 * w1a.x;  acc[1] += x0 * w0a.y + x1 * w1a.y;
    acc[2] += x0 * w0a.z + x1 * w1a.z;  acc[3] += x0 * w0a.w + x1 * w1a.w;
    acc[4] += x0 * w0b.x + x1 * w1b.x;  acc[5] += x0 * w0b.y + x1 * w1b.y;
    acc[6] += x0 * w0b.z + x1 * w1b.z;  acc[7] += x0 * w0b.w + x1 * w1b.w;
  }
#pragma unroll
  for (int m = 1; m < 64; m <<= 1) ss += __shfl_xor(ss, m);
#pragma unroll
  for (int j = 0; j < 8; ++j)
#pragma unroll
    for (int m = 1; m < 64; m <<= 1) acc[j] += __shfl_xor(acc[j], m);
  if (lane == 0) {
    const float s = rsqrtf(ss * (1.f / 1024.f) + 1e-6f);
    rs[r] = s;
#pragma unroll
    for (int j = 0; j < 8; ++j) beta[(size_t)r * 8 + j] = 2.f / (1.f + expf(-acc[j] * s));
  }
}

// -------- fused rowscale + beta (layer >=1) --------------------------------
__global__ __launch_bounds__(256) void rsbeta_k(const f16* __restrict__ x, const float* __restrict__ Wb2,
                                                float* __restrict__ rs, float* __restrict__ beta) {
  const int tid = threadIdx.x, lane = tid & 63, wv = tid >> 6;
  const int r = blockIdx.x * 4 + wv;
  const f16* row = x + (size_t)r * 1024 + lane * 16;
  const h8 v0 = *(const h8*)(row);
  const h8 v1 = *(const h8*)(row + 8);
  const float* wb = Wb2 + (size_t)(lane * 16) * 8;
  float ss = 0.f;
  float acc[8] = {};
#pragma unroll
  for (int e = 0; e < 8; ++e) {
    const float x0 = (float)v0[e], x1 = (float)v1[e];
    ss += x0 * x0 + x1 * x1;
    const float4 w0a = *(const float4*)(wb + e * 8);
    const float4 w0b = *(const float4*)(wb + e * 8 + 4);
    const float4 w1a = *(const float4*)(wb + (e + 8) * 8);
    const float4 w1b = *(const float4*)(wb + (e + 8) * 8 + 4);
    acc[0] += x0 * w0a.x + x1 * w1a.x;  acc[1] += x0 * w0a.y + x1 * w1a.y;
    acc[2] += x0 * w0a.z + x1 * w1a.z;  acc[3] += x0 * w0a.w + x1 * w1a.w;
    acc[4] += x0 * w0b.x + x1 * w1b.x;  acc[5] += x0 * w0b.y + x1 * w1b.y;
    acc[6] += x0 * w0b.z + x1 * w1b.z;  acc[7] += x0 * w0b.w + x1 * w1b.w;
  }
#pragma unroll
  for (int m = 1; m < 64; m <<= 1) ss += __shfl_xor(ss, m);
#pragma unroll
  for (int j = 0; j < 8; ++j)
#pragma unroll
    for (int m = 1; m < 64; m <<= 1) acc[j] += __shfl_xor(acc[j], m);
  if (lane == 0) {
    const float s = rsqrtf(ss * (1.f / 1024.f) + 1e-6f);
    rs[r] = s;
#pragma unroll
    for (int j = 0; j < 8; ++j) beta[(size_t)r * 8 + j] = 2.f / (1.f + expf(-acc[j] * s));
  }
}

// ---------------- final RMSNorm (f16 in, f32 out) --------------------------
__global__ __launch_bounds__(256) void rmsnorm_f(const f16* __restrict__ x, const float* __restrict__ w,
                                                 float* __restrict__ out) {
  const int r = blockIdx.x, tid = threadIdx.x;
  const h4 xv = *(const h4*)(x + (size_t)r * 1024 + tid * 4);
  const float v0 = (float)xv[0], v1 = (float)xv[1], v2 = (float)xv[2], v3 = (float)xv[3];
  float ss = v0 * v0 + v1 * v1 + v2 * v2 + v3 * v3;
#pragma unroll
  for (int m = 1; m < 64; m <<= 1) ss += __shfl_xor(ss, m);
  __shared__ float red[4];
  if ((tid & 63) == 0) red[tid >> 6] = ss;
  __syncthreads();
  const float scale = rsqrtf((red[0] + red[1] + red[2] + red[3]) * (1.f / 1024.f) + 1e-6f);
  const float4 w4 = *(const float4*)(w + tid * 4);
  *(float4*)(out + (size_t)r * 1024 + tid * 4) =
      make_float4(v0 * scale * w4.x, v1 * scale * w4.y, v2 * scale * w4.z, v3 * scale * w4.w);
}

// ---------------- per-head RMSNorm -----------------------------------------
__global__ __launch_bounds__(256) void onorm_k(const f16* __restrict__ o, const float* __restrict__ w,
                                               f16* __restrict__ ob) {
  const int r = blockIdx.x, tid = threadIdx.x;
  const int head = tid >> 5, l32 = tid & 31;
  const size_t base = (size_t)r * 1024 + head * 128 + l32 * 4;
  const h4 xv = *(const h4*)(o + base);
  const float v0 = (float)xv[0], v1 = (float)xv[1], v2 = (float)xv[2], v3 = (float)xv[3];
  float ss = v0 * v0 + v1 * v1 + v2 * v2 + v3 * v3;
#pragma unroll
  for (int m = 1; m <= 16; m <<= 1) ss += __shfl_xor(ss, m);
  const float sc = rsqrtf(ss * (1.f / 128.f) + 1e-6f);
  const float4 w4 = *(const float4*)(w + l32 * 4);
  h4 out = {(f16)(v0 * sc * w4.x), (f16)(v1 * sc * w4.y), (f16)(v2 * sc * w4.z), (f16)(v3 * sc * w4.w)};
  *(h4*)(ob + base) = out;
}

// ------ W[K][N] f32 -> Wt[N][K] f16 (both layers via blockIdx.z) -----------
template<int FOLD>
__global__ __launch_bounds__(256) void transpose_k(const float* __restrict__ W, const float* __restrict__ rw,
                                                   f16* __restrict__ Wt, int K, int N,
                                                   size_t inLS, size_t outLS) {
  __shared__ float tile[32][33];
  const int l = blockIdx.z;
  W += (size_t)l * inLS;
  Wt += (size_t)l * outLS;
  if (FOLD) rw += (size_t)l * 1024;
  const int n0 = blockIdx.x * 32, k0 = blockIdx.y * 32;
  const int tx = threadIdx.x & 31, ty = threadIdx.x >> 5;
#pragma unroll
  for (int i = 0; i < 32; i += 8) {
    float v = W[(size_t)(k0 + ty + i) * N + n0 + tx];
    if (FOLD) v *= rw[k0 + ty + i];
    tile[ty + i][tx] = v;
  }
  __syncthreads();
#pragma unroll
  for (int i = 0; i < 32; i += 8) Wt[(size_t)(n0 + ty + i) * K + k0 + tx] = (f16)tile[tx][ty + i];
}

// ---------------- Wb' = diag(n1w) Wb (both layers) -------------------------
__global__ __launch_bounds__(256) void bweight_k(const float* __restrict__ Wb, const float* __restrict__ n1w,
                                                 float* __restrict__ Wb2) {
  const int idx = blockIdx.x * 256 + threadIdx.x;
  const int l = idx >> 13, e = idx & 8191;
  Wb2[idx] = Wb[idx] * n1w[l * 1024 + (e >> 3)];
}

__global__ void fill_k(float* p, int n, float v) {
  const int i = blockIdx.x * 256 + threadIdx.x;
  if (i < n) p[i] = v;
}

// ---------------- Phase A: WY transform ------------------------------------
DEV f4 mm16(const f16* A, int as, const f16* B, f4 c, int l15, int l4) {
  h4 a = *(const h4*)(A + l15 * as + l4 * 4);
  h4 b = *(const h4*)(B + l15 * 20 + l4 * 4);
  return __builtin_amdgcn_mfma_f32_16x16x16f16(a, b, c, 0, 0, 0);
}
DEV void wr_T(f16* slot, f4 acc, int l15, int l4, float sgn) {
  h4 v = {(f16)(sgn * acc[0]), (f16)(sgn * acc[1]), (f16)(sgn * acc[2]), (f16)(sgn * acc[3])};
  *(h4*)(slot + l15 * 20 + l4 * 4) = v;
}
DEV void wr_Tb(f16* Tb, int bi, int bj, f4 acc, const float* betas, int l15, int l4, float sgn) {
  const float bc = betas[bj * 16 + l15];
#pragma unroll
  for (int q = 0; q < 4; ++q)
    Tb[(bi * 16 + l4 * 4 + q) * 72 + bj * 16 + l15] = (f16)(sgn * acc[q] * bc);
}

__global__ __launch_bounds__(256) void phaseA(const f16* __restrict__ kb, const f16* __restrict__ qb,
                                              const f16* __restrict__ vb, const float* __restrict__ beta,
                                              f16* __restrict__ wbuf, f16* __restrict__ utbuf,
                                              f16* __restrict__ pbuf, f16* __restrict__ ktbuf) {
  const int blk = blockIdx.x;
  const int c = blk >> 5, bh = blk & 31;
  const int b = bh >> 3, h = bh & 7;
  const int tid = threadIdx.x, lane = tid & 63, wv = tid >> 6;
  const int l15 = lane & 15, l4 = lane >> 4;

  __shared__ __align__(16) f16 Ks[64 * 128];
  __shared__ __align__(16) f16 QVs[64 * 128];
  __shared__ __align__(16) f16 Abuf[64 * 68];
  __shared__ __align__(16) f16 Dr[4][16 * 20];
  __shared__ __align__(16) f16 Dt[4][16 * 20];
  __shared__ __align__(16) f16 Tp[3][16 * 20];
  __shared__ __align__(16) f16 Xp[3][16 * 20];
  __shared__ __align__(16) f16 Tb[64 * 72];
  __shared__ float betas[64];

  const size_t rowstr = (size_t)Bb_ * Dd;
  const size_t gbase = ((size_t)(c * 64) * Bb_ + b) * Dd + h * 128;

#pragma unroll
  for (int i = 0; i < 4; ++i) {
    const int ch = tid + i * 256;
    const int rr = ch >> 4, kc = ch & 15;
    *(h8*)(Ks + ch * 8) = *(const h8*)(kb + gbase + (size_t)rr * rowstr + kc * 8);
    *(h8*)(QVs + ch * 8) = *(const h8*)(qb + gbase + (size_t)rr * rowstr + kc * 8);
  }
  for (int i = tid; i < 64 * 72; i += 256) Tb[i] = (f16)0.f;
  if (tid < 64) betas[tid] = beta[((size_t)(c * 64 + tid) * Bb_ + b) * Hh + h];
  __syncthreads();

  f4 accS[4] = {}, accP[4] = {};
  const int arow = wv * 16 + l15;
#pragma unroll
  for (int kc = 0; kc < 4; ++kc) {
    const int c4 = kc * 4 + l4;
    const h8 aK = *(const h8*)(Ks + arow * 128 + swz16(arow, c4) * 8);
    const h8 aQ = *(const h8*)(QVs + arow * 128 + swz16(arow, c4) * 8);
#pragma unroll
    for (int f = 0; f < 4; ++f) {
      const int brow = f * 16 + l15;
      const h8 bK = *(const h8*)(Ks + brow * 128 + swz16(brow, c4) * 8);
      accS[f] = __builtin_amdgcn_mfma_f32_16x16x32_f16(aK, bK, accS[f], 0, 0, 0);
      accP[f] = __builtin_amdgcn_mfma_f32_16x16x32_f16(aQ, bK, accP[f], 0, 0, 0);
    }
  }
  const size_t pbase = (((size_t)bh * NC + c) * 64) * 64;
#pragma unroll
  for (int f = 0; f < 4; ++f) {
#pragma unroll
    for (int q = 0; q < 4; ++q) {
      const int i = wv * 16 + l4 * 4 + q;
      const int j = f * 16 + l15;
      Abuf[i * 68 + j] = (f16)((j < i) ? betas[i] * accS[f][q] : 0.f);
      pbuf[pbase + (size_t)i * 64 + j] = (f16)((j <= i) ? accP[f][q] : 0.f);
    }
  }
  __syncthreads();

#pragma unroll
  for (int i = 0; i < 4; ++i) {
    const int ch = tid + i * 256;
    const int rr = ch >> 4, kc = ch & 15;
    *(h8*)(QVs + ch * 8) = *(const h8*)(vb + gbase + (size_t)rr * rowstr + kc * 8);
  }

  {
    const int bi = wv;
    const int cc = l15;
    const f16* Ad = Abuf + (bi * 16) * 68 + bi * 16;
    float t[16];
    t[0] = (cc == 0) ? 1.f : 0.f;
#pragma unroll
    for (int i = 1; i < 16; ++i) {
      float s = (cc == i) ? 1.f : 0.f;
#pragma unroll
      for (int j = 0; j < i; ++j) s -= (float)Ad[i * 68 + j] * t[j];
      t[i] = s;
    }
    if (lane < 16) {
#pragma unroll
      for (int j4 = 0; j4 < 4; ++j4) {
        h4 v = {(f16)t[j4 * 4], (f16)t[j4 * 4 + 1], (f16)t[j4 * 4 + 2], (f16)t[j4 * 4 + 3]};
        *(h4*)(&Dt[bi][cc * 20 + j4 * 4]) = v;
      }
      const float bc = betas[bi * 16 + cc];
#pragma unroll
      for (int j = 0; j < 16; ++j) {
        Dr[bi][j * 20 + cc] = (f16)t[j];
        Tb[(bi * 16 + j) * 72 + bi * 16 + cc] = (f16)(t[j] * bc);
      }
    }
  }
  __syncthreads();

  const f16* AB10 = Abuf + 16 * 68 + 0;
  const f16* AB20 = Abuf + 32 * 68 + 0;
  const f16* AB21 = Abuf + 32 * 68 + 16;
  const f16* AB30 = Abuf + 48 * 68 + 0;
  const f16* AB31 = Abuf + 48 * 68 + 16;
  const f16* AB32 = Abuf + 48 * 68 + 32;
  f4 z = {};
  f4 x20, x30;

  if (wv == 0) wr_T(Xp[0], mm16(AB10, 68, Dt[0], z, l15, l4), l15, l4, 1.f);
  if (wv == 1) wr_T(Xp[1], mm16(AB21, 68, Dt[1], z, l15, l4), l15, l4, 1.f);
  if (wv == 2) wr_T(Xp[2], mm16(AB32, 68, Dt[2], z, l15, l4), l15, l4, 1.f);
  if (wv == 3) x20 = mm16(AB20, 68, Dt[0], z, l15, l4);
  __syncthreads();
  if (wv == 0) { f4 r = mm16(Dr[1], 20, Xp[0], z, l15, l4); wr_T(Tp[0], r, l15, l4, -1.f); wr_Tb(Tb, 1, 0, r, betas, l15, l4, -1.f); }
  if (wv == 1) { f4 r = mm16(Dr[2], 20, Xp[1], z, l15, l4); wr_T(Tp[1], r, l15, l4, -1.f); wr_Tb(Tb, 2, 1, r, betas, l15, l4, -1.f); }
  if (wv == 2) { f4 r = mm16(Dr[3], 20, Xp[2], z, l15, l4); wr_Tb(Tb, 3, 2, r, betas, l15, l4, -1.f); }
  if (wv == 3) x30 = mm16(AB30, 68, Dt[0], z, l15, l4);
  __syncthreads();
  if (wv == 3) wr_T(Xp[0], mm16(AB21, 68, Tp[0], x20, l15, l4), l15, l4, 1.f);
  if (wv == 1) { f4 r = mm16(AB31, 68, Dt[1], z, l15, l4); r = mm16(AB32, 68, Tp[1], r, l15, l4); wr_T(Xp[1], r, l15, l4, 1.f); }
  __syncthreads();
  if (wv == 3) { f4 r = mm16(Dr[2], 20, Xp[0], z, l15, l4); wr_T(Tp[2], r, l15, l4, -1.f); wr_Tb(Tb, 2, 0, r, betas, l15, l4, -1.f); }
  if (wv == 1) { f4 r = mm16(Dr[3], 20, Xp[1], z, l15, l4); wr_Tb(Tb, 3, 1, r, betas, l15, l4, -1.f); }
  __syncthreads();
  if (wv == 3) { f4 r = mm16(AB31, 68, Tp[0], x30, l15, l4); r = mm16(AB32, 68, Tp[2], r, l15, l4); wr_T(Xp[2], r, l15, l4, 1.f); }
  __syncthreads();
  if (wv == 3) { f4 r = mm16(Dr[3], 20, Xp[2], z, l15, l4); wr_Tb(Tb, 3, 0, r, betas, l15, l4, -1.f); }
  __syncthreads();

  const size_t wub = ((size_t)bh * NC + c) * 8192;
  const int koff = l4 * 8;
  f4 wacc[8] = {}, uacc[8] = {};
#pragma unroll
  for (int kc = 0; kc < 2; ++kc) {
    const h8 aT = *(const h8*)(Tb + (wv * 16 + l15) * 72 + kc * 32 + koff);
#pragma unroll
    for (int f = 0; f < 8; ++f) {
      const int d = f * 16 + l15, cD = d >> 3, d7 = d & 7;
      h8 bK, bV;
#pragma unroll
      for (int j = 0; j < 8; ++j) {
        const int t2 = kc * 32 + koff + j;
        const int pos = t2 * 128 + swz16(t2, cD) * 8 + d7;
        bK[j] = Ks[pos];
        bV[j] = QVs[pos];
      }
      wacc[f] = __builtin_amdgcn_mfma_f32_16x16x32_f16(aT, bK, wacc[f], 0, 0, 0);
      uacc[f] = __builtin_amdgcn_mfma_f32_16x16x32_f16(aT, bV, uacc[f], 0, 0, 0);
    }
  }
#pragma unroll
  for (int f = 0; f < 8; ++f) {
    const int d = f * 16 + l15, cD = d >> 3, d7 = d & 7;
#pragma unroll
    for (int q = 0; q < 4; ++q) {
      const int i = wv * 16 + l4 * 4 + q;
      wbuf[wub + (size_t)i * 128 + swz16(i, cD) * 8 + d7] = (f16)wacc[f][q];
    }
    h4 uv = {(f16)uacc[f][0], (f16)uacc[f][1], (f16)uacc[f][2], (f16)uacc[f][3]};
    *(h4*)(utbuf + wub + (size_t)d * 64 + wv * 16 + l4 * 4) = uv;
  }

#pragma unroll
  for (int i2 = 0; i2 < 4; ++i2) {
    const int ch = tid + i2 * 256;
    const int dp = ch & 127, c2 = ch >> 7;
    h8 v;
#pragma unroll
    for (int j = 0; j < 8; ++j) {
      const int i = c2 * 8 + j;
      v[j] = Ks[i * 128 + swz16(i, dp >> 3) * 8 + (dp & 7)];
    }
    *(h8*)(ktbuf + wub + (size_t)dp * 64 + (c2 ^ (dp & 7)) * 8) = v;
  }
}

// ---------------- Phase B: chunk recurrence (g in 0..7, 16 cols) -----------
__global__ __launch_bounds__(256) void phaseB(const f16* __restrict__ qb, const f16* __restrict__ ktbuf,
                                              const f16* __restrict__ wbuf, const f16* __restrict__ utbuf,
                                              const f16* __restrict__ pbuf, f16* __restrict__ obuf) {
  const int blk = blockIdx.x;
  const int bh = blk & 31, g = blk >> 5;
  const int b = bh >> 3, h = bh & 7;
  const int tid = threadIdx.x, lane = tid & 63, wv = tid >> 6;
  const int l15 = lane & 15, l4 = lane >> 4;

  __shared__ __align__(16) f16 Ws[2][8192];
  __shared__ __align__(16) f16 Qs[2][8192];
  __shared__ __align__(16) f16 Kts[2][8192];
  __shared__ __align__(16) f16 Rt[16 * 72];
  __shared__ __align__(16) f16 Ms[16 * 136];

  for (int i = tid; i < 16 * 136; i += 256) Ms[i] = (f16)0.f;
  f4 macc2[2] = {};

  const int arow = wv * 16 + l15;
  const int koff = l4 * 8;

  auto STAGE = [&](int c2, int buf) {
#pragma unroll
    for (int i = 0; i < 4; ++i) {
      const int ch = tid + i * 256;
      const size_t tb = ((size_t)bh * NC + c2) * 8192;
      __builtin_amdgcn_global_load_lds(AS1(wbuf + tb + ch * 8), AS3(Ws[buf] + ch * 8), 16, 0, 0);
      __builtin_amdgcn_global_load_lds(AS1(ktbuf + tb + ch * 8), AS3(Kts[buf] + ch * 8), 16, 0, 0);
      const int rr = ch >> 4, kc2 = ch & 15;
      __builtin_amdgcn_global_load_lds(AS1(qb + ((size_t)((c2 * 64 + rr) * 4 + b)) * 1024 + h * 128 + kc2 * 8),
                                       AS3(Qs[buf] + ch * 8), 16, 0, 0);
    }
  };

  STAGE(0, 0);
  asm volatile("s_waitcnt vmcnt(0)" ::: "memory");
  __builtin_amdgcn_s_barrier();

  for (int c = 0; c < NC; ++c) {
    const int cur = c & 1, nxt = cur ^ 1;
    const size_t pcb = ((size_t)bh * NC + c) * 4096;
    const h8 aP0 = *(const h8*)(pbuf + pcb + arow * 64 + koff);
    const h8 aP1 = *(const h8*)(pbuf + pcb + arow * 64 + 32 + koff);
    const size_t ucb = ((size_t)bh * NC + c) * 8192;
    const h4 u0 = *(const h4*)(utbuf + ucb + (size_t)(g * 16 + l15) * 64 + wv * 16 + l4 * 4);
    asm volatile("s_waitcnt vmcnt(3)" ::: "memory");
    asm volatile("s_waitcnt lgkmcnt(0)" ::: "memory");
    __builtin_amdgcn_s_barrier();
    if (c + 1 < NC) STAGE(c + 1, nxt);

    f4 accR = {}, accO = {};
    __builtin_amdgcn_s_setprio(1);
#pragma unroll
    for (int kc = 0; kc < 4; ++kc) {
      const int c4 = kc * 4 + l4;
      const h8 aW = *(const h8*)(Ws[cur] + arow * 128 + swz16(arow, c4) * 8);
      const h8 aQ = *(const h8*)(Qs[cur] + arow * 128 + swz16(arow, c4) * 8);
      const h8 bM = *(const h8*)(Ms + l15 * 136 + kc * 32 + koff);
      accR = __builtin_amdgcn_mfma_f32_16x16x32_f16(aW, bM, accR, 0, 0, 0);
      accO = __builtin_amdgcn_mfma_f32_16x16x32_f16(aQ, bM, accO, 0, 0, 0);
    }
    __builtin_amdgcn_s_setprio(0);
    if (c + 1 < NC) asm volatile("s_waitcnt vmcnt(12)" ::: "memory");
    else            asm volatile("s_waitcnt vmcnt(0)" ::: "memory");
    {
      h4 rw;
#pragma unroll
      for (int q = 0; q < 4; ++q) {
        const float rv = (float)u0[q] - accR[q];
        rw[q] = (f16)rv;
      }
      *(h4*)(Rt + l15 * 72 + wv * 16 + l4 * 4) = rw;
    }
    asm volatile("s_waitcnt lgkmcnt(0)" ::: "memory");
    __builtin_amdgcn_s_barrier();

#pragma unroll
    for (int kc = 0; kc < 2; ++kc) {
      const h8 aP = kc ? aP1 : aP0;
      const h8 bR = *(const h8*)(Rt + l15 * 72 + kc * 32 + koff);
      accO = __builtin_amdgcn_mfma_f32_16x16x32_f16(aP, bR, accO, 0, 0, 0);
    }
#pragma unroll
    for (int q = 0; q < 4; ++q) {
      const int i = wv * 16 + l4 * 4 + q;
      obuf[((size_t)(c * 64 + i) * Bb_ + b) * Dd + h * 128 + g * 16 + l15] = (f16)accO[q];
    }

#pragma unroll
    for (int kc = 0; kc < 2; ++kc) {
      const h8 aR0 = *(const h8*)(Rt + l15 * 72 + kc * 32 + koff);
#pragma unroll
      for (int cf = 0; cf < 2; ++cf) {
        const int kcol = wv * 32 + cf * 16 + l15;
        const int c2 = kc * 4 + l4;
        const h8 bKv = *(const h8*)(Kts[cur] + kcol * 64 + (c2 ^ (kcol & 7)) * 8);
        macc2[cf] = __builtin_amdgcn_mfma_f32_16x16x32_f16(aR0, bKv, macc2[cf], 0, 0, 0);
      }
    }
#pragma unroll
    for (int cf = 0; cf < 2; ++cf)
#pragma unroll
      for (int q = 0; q < 4; ++q) {
        const int cr = l4 * 4 + q;
        const int kcol = wv * 32 + cf * 16 + l15;
        Ms[cr * 136 + kcol] = (f16)macc2[cf][q];
      }
  }
}

// ---------------------------------------------------------------------------
extern "C" void kernel_launch(void* const* d_in, const int* in_sizes, int n_in,
                              void* d_out, int out_size, void* d_ws, size_t ws_size,
                              hipStream_t stream) {
  (void)in_sizes; (void)n_in;
  const float* input = (const float*)d_in[0];
  const float* Wq = (const float*)d_in[1];
  const float* Wk = (const float*)d_in[2];
  const float* Wv = (const float*)d_in[3];
  const float* Wb = (const float*)d_in[4];
  const float* Wo = (const float*)d_in[5];
  const float* onw = (const float*)d_in[6];
  const float* n1w = (const float*)d_in[7];
  const float* n2w = (const float*)d_in[8];
  const float* Wg = (const float*)d_in[9];
  const float* Wd = (const float*)d_in[10];
  const float* fnw = (const float*)d_in[11];

  char* ws = (char*)d_ws;
  size_t off = 0;
  auto alloc = [&](size_t bytes) { void* p = ws + off; off += (bytes + 255) & ~(size_t)255; return p; };
  const size_t RD = 8192ull * 1024ull;
  f16*  x     = (f16*)alloc(RD * 2);
  f16*  qb    = (f16*)alloc(RD * 2);
  f16*  kbuf  = (f16*)alloc(RD * 2);
  f16*  vbuf  = (f16*)alloc(RD * 2);
  float* beta = (float*)alloc(8192ull * 8 * 4);
  float* rs   = (float*)alloc(8192ull * 4);
  float* rsq  = (float*)alloc(8192ull * 4);
  float* Wb2  = (float*)alloc(2ull * 1024 * 8 * 4);
  f16*  wbuf  = (f16*)alloc(RD * 2);
  f16*  utbuf = (f16*)alloc(RD * 2);
  f16*  ktbuf = (f16*)alloc(RD * 2);
  f16*  pbuf  = (f16*)alloc(32ull * 32 * 64 * 64 * 2);
  char* arena = (char*)alloc(3 * RD * 2);
  f16*  WqkvT = (f16*)alloc(2ull * 3072 * 1024 * 2);
  f16*  WoT   = (f16*)alloc(2ull * 1024 * 1024 * 2);
  f16*  WgT   = (f16*)alloc(2ull * 5632 * 1024 * 2);
  f16*  WdT   = (f16*)alloc(2ull * 1024 * 2816 * 2);
  if (off > ws_size) {
    fill_k<<<(out_size + 255) / 256, 256, 0, stream>>>((float*)d_out, out_size, 1.0e6f);
    return;
  }
  f16* obuf = (f16*)arena;
  f16* my = qb;
  f16* ob = wbuf;

  // ---- weight prep (both layers) ----
  transpose_k<1><<<dim3(32, 32, 2), 256, 0, stream>>>(Wq, n1w, WqkvT, 1024, 1024, 1024ull * 1024, 3072ull * 1024);
  transpose_k<1><<<dim3(32, 32, 2), 256, 0, stream>>>(Wk, n1w, WqkvT + 1024ull * 1024, 1024, 1024, 1024ull * 1024, 3072ull * 1024);
  transpose_k<1><<<dim3(32, 32, 2), 256, 0, stream>>>(Wv, n1w, WqkvT + 2048ull * 1024, 1024, 1024, 1024ull * 1024, 3072ull * 1024);
  transpose_k<0><<<dim3(32, 32, 2), 256, 0, stream>>>(Wo, nullptr, WoT, 1024, 1024, 1024ull * 1024, 1024ull * 1024);
  transpose_k<1><<<dim3(176, 32, 2), 256, 0, stream>>>(Wg, n2w, WgT, 1024, 5632, 1024ull * 5632, 5632ull * 1024);
  transpose_k<0><<<dim3(32, 88, 2), 256, 0, stream>>>(Wd, nullptr, WdT, 2816, 1024, 2816ull * 1024, 1024ull * 2816);
  bweight_k<<<64, 256, 0, stream>>>(Wb, n1w, Wb2);

  // ---- fused convert + layer-0 rowscale/beta ----
  cvt_row<<<2048, 256, 0, stream>>>(input, x, Wb2, rs, beta);

  for (int l = 0; l < 2; ++l) {
    const f16* WqkvTl = WqkvT + (size_t)l * 3072 * 1024;
    const f16* WoTl   = WoT + (size_t)l * 1024 * 1024;
    const f16* WgTl   = WgT + (size_t)l * 5632 * 1024;
    const f16* WdTl   = WdT + (size_t)l * 1024 * 2816;

    if (l > 0) rsbeta_k<<<2048, 256, 0, stream>>>(x, Wb2 + (size_t)l * 8192, rs, beta);
    gemmQKV<<<32 * 24, 512, 0, stream>>>(x, WqkvTl, rs, qb, kbuf, vbuf, 1024, 24);
    phaseA<<<1024, 256, 0, stream>>>(kbuf, qb, vbuf, beta, wbuf, utbuf, pbuf, ktbuf);
    phaseB<<<256, 256, 0, stream>>>(qb, ktbuf, wbuf, utbuf, pbuf, obuf);
    onorm_k<<<8192, 256, 0, stream>>>(obuf, onw + l * 128, ob);
    hipMemsetAsync(rsq, 0, 8192 * 4, stream);
    gemm2<1, 0, 1><<<32 * 8, 512, 0, stream>>>(ob, WoTl, x, rsq, 8192, 1024, 1024, 8);

    gemmGLU<<<32 * 22, 512, 0, stream>>>(x, WgTl, rsq, my, 1024, 22);
    gemm2<1, 0, 0><<<32 * 8, 512, 0, stream>>>(my, WdTl, x, nullptr, 8192, 1024, 2816, 8);
  }
  rmsnorm_f<<<8192, 256, 0, stream>>>(x, fnw, (float*)d_out);
}